// Round 8
// baseline (158.974 us; speedup 1.0000x reference)
//
#include <hip/hip_runtime.h>

typedef float f32x4 __attribute__((ext_vector_type(4)));
typedef short bf16x8 __attribute__((ext_vector_type(8)));

#define MFMA16 __builtin_amdgcn_mfma_f32_16x16x32_bf16

// ---------- bf16 helpers (manual RNE, verified rounds 2-7) ----------
__device__ __forceinline__ unsigned short f2bf(float f) {
    union { float f; unsigned int i; } x;
    x.f = f;
    unsigned int i = x.i;
    unsigned int lsb = (i >> 16) & 1u;
    i += 0x7FFFu + lsb;
    return (unsigned short)(i >> 16);
}
__device__ __forceinline__ bf16x8 cvt8(float4 a, float4 b) {
    union { bf16x8 v; unsigned short u[8]; } r;
    r.u[0] = f2bf(a.x); r.u[1] = f2bf(a.y); r.u[2] = f2bf(a.z); r.u[3] = f2bf(a.w);
    r.u[4] = f2bf(b.x); r.u[5] = f2bf(b.y); r.u[6] = f2bf(b.z); r.u[7] = f2bf(b.w);
    return r.v;
}

// ws layout (bytes):
//   0         : WqkvT bf16 [768][256]      (393216)
//   393216    : WoutT bf16 [256][256]      (131072)
//   524288    : bias_tab f32 [64][64]      (16384)
//   540672    : QKV bf16, per window-head (wh = wid*8+h), 12288 B each:
//               Q[64][32] @0 (overwritten by O after attention),
//               K[64][32] @4096, VT[32][64] @8192
#define WS_NEED        540672
#define WS3_NEED       101203968
#define WOUTT_SHORT_OFF 196608
#define QKV_SHORT_OFF   270336

// =====================================================================
// Prep: transpose weights to bf16 n-major; expand PE to [q][j] table.
// =====================================================================
__global__ void prep_kernel(const float* __restrict__ wqkv,
                            const float* __restrict__ wout,
                            const float* __restrict__ pe,
                            unsigned short* __restrict__ wsT,
                            float* __restrict__ bias_tab)
{
    const int b = blockIdx.x, tid = threadIdx.x;
    if (b < 256) {
        const int w = tid >> 6, l = tid & 63;
        const int r = b * 4 + w;               // output row (n)
        const float* src;
        unsigned short* dst;
        int stride;
        if (r < 768) { src = wqkv + r; stride = 768; dst = wsT + (size_t)r * 256; }
        else { int n = r - 768; src = wout + n; stride = 256;
               dst = wsT + WOUTT_SHORT_OFF + (size_t)n * 256; }
        ushort4 v;
        v.x = f2bf(src[(size_t)(l * 4 + 0) * stride]);
        v.y = f2bf(src[(size_t)(l * 4 + 1) * stride]);
        v.z = f2bf(src[(size_t)(l * 4 + 2) * stride]);
        v.w = f2bf(src[(size_t)(l * 4 + 3) * stride]);
        *reinterpret_cast<ushort4*>(dst + l * 4) = v;
    } else {
        #pragma unroll
        for (int i = 0; i < 16; ++i) {
            int idx = tid + i * 256;           // q*64 + j
            int q = idx >> 6, j = idx & 63;
            int dy = (j >> 3) - (q >> 3) + 7;
            int dx = (j & 7) - (q & 7) + 7;
            bias_tab[idx] = pe[dy * 15 + dx];
        }
    }
}

// =====================================================================
// qkv6: grid 3072 = p*1024 + wid (p = matrix Q/K/V; a window's 3
// blocks share an XCD for X-tile L2 reuse). proj4-identical GEMM:
// stage X once, one continuous 8-step K-loop, wave = 64 cols
// (heads 2wv, 2wv+1 of matrix p), 4 prefetched B streams.
// Verified epilogues: Q/K LDS-bounce -> [tok][32]; V -> VT[ch][tok].
// LDS 43008 B.
// =====================================================================
__global__ __launch_bounds__(256, 3)
void qkv6(const float* __restrict__ x,
          const unsigned short* __restrict__ wqkvT,
          unsigned short* __restrict__ qkv)
{
    __shared__ __align__(16) unsigned short sX[64][264];
    __shared__ __align__(16) unsigned short sB[4][16][72];  // wave-private bounce

    const int tid  = threadIdx.x;
    const int lane = tid & 63;
    const int wv   = tid >> 6;
    const int ln   = lane & 15;
    const int lg   = lane >> 4;

    const int p   = blockIdx.x >> 10;      // matrix 0=Q 1=K 2=V
    const int wid = blockIdx.x & 1023;
    const int blw = wid >> 6;
    const int whr = (wid >> 3) & 7;
    const int wwc = wid & 7;
    const int tok_base = blw * 4096 + whr * 512 + wwc * 8;
    // token(i) = tok_base + (i>>3)*64 + (i&7)

    // B pointers: rows n = p*256 + wv*64 + j*16 + ln of WqkvT
    const unsigned short* b0 =
        wqkvT + (size_t)(p * 256 + wv * 64 + ln) * 256 + lg * 8;
    const unsigned short* b1 = b0 + 16 * 256;
    const unsigned short* b2 = b0 + 32 * 256;
    const unsigned short* b3 = b0 + 48 * 256;
    bf16x8 bc0 = *reinterpret_cast<const bf16x8*>(b0);
    bf16x8 bc1 = *reinterpret_cast<const bf16x8*>(b1);
    bf16x8 bc2 = *reinterpret_cast<const bf16x8*>(b2);
    bf16x8 bc3 = *reinterpret_cast<const bf16x8*>(b3);

    // ---- stage X once (64 x 256 f32 -> bf16) ----
    #pragma unroll
    for (int it = 0; it < 8; ++it) {
        int idx = tid + (it << 8);
        int row = idx >> 5, c8 = idx & 31;
        int tok = tok_base + ((row >> 3) << 6) + (row & 7);
        const float* pp = x + (size_t)tok * 256 + c8 * 8;
        float4 a = *reinterpret_cast<const float4*>(pp);
        float4 b = *reinterpret_cast<const float4*>(pp + 4);
        *reinterpret_cast<bf16x8*>(&sX[row][c8 * 8]) = cvt8(a, b);
    }
    __syncthreads();

    f32x4 acc[4][4];
    #pragma unroll
    for (int m = 0; m < 4; ++m)
        #pragma unroll
        for (int j = 0; j < 4; ++j) acc[m][j] = (f32x4)(0.f);

    #pragma unroll
    for (int st = 0; st < 8; ++st) {
        const int ko = st * 32 + lg * 8;
        bf16x8 a0 = *reinterpret_cast<const bf16x8*>(&sX[     ln][ko]);
        bf16x8 a1 = *reinterpret_cast<const bf16x8*>(&sX[16 + ln][ko]);
        bf16x8 a2 = *reinterpret_cast<const bf16x8*>(&sX[32 + ln][ko]);
        bf16x8 a3 = *reinterpret_cast<const bf16x8*>(&sX[48 + ln][ko]);
        bf16x8 bn0 = bc0, bn1 = bc1, bn2 = bc2, bn3 = bc3;
        if (st < 7) {
            bn0 = *reinterpret_cast<const bf16x8*>(b0 + (st + 1) * 32);
            bn1 = *reinterpret_cast<const bf16x8*>(b1 + (st + 1) * 32);
            bn2 = *reinterpret_cast<const bf16x8*>(b2 + (st + 1) * 32);
            bn3 = *reinterpret_cast<const bf16x8*>(b3 + (st + 1) * 32);
        }
        acc[0][0] = MFMA16(a0, bc0, acc[0][0], 0, 0, 0);
        acc[1][0] = MFMA16(a1, bc0, acc[1][0], 0, 0, 0);
        acc[2][0] = MFMA16(a2, bc0, acc[2][0], 0, 0, 0);
        acc[3][0] = MFMA16(a3, bc0, acc[3][0], 0, 0, 0);
        acc[0][1] = MFMA16(a0, bc1, acc[0][1], 0, 0, 0);
        acc[1][1] = MFMA16(a1, bc1, acc[1][1], 0, 0, 0);
        acc[2][1] = MFMA16(a2, bc1, acc[2][1], 0, 0, 0);
        acc[3][1] = MFMA16(a3, bc1, acc[3][1], 0, 0, 0);
        acc[0][2] = MFMA16(a0, bc2, acc[0][2], 0, 0, 0);
        acc[1][2] = MFMA16(a1, bc2, acc[1][2], 0, 0, 0);
        acc[2][2] = MFMA16(a2, bc2, acc[2][2], 0, 0, 0);
        acc[3][2] = MFMA16(a3, bc2, acc[3][2], 0, 0, 0);
        acc[0][3] = MFMA16(a0, bc3, acc[0][3], 0, 0, 0);
        acc[1][3] = MFMA16(a1, bc3, acc[1][3], 0, 0, 0);
        acc[2][3] = MFMA16(a2, bc3, acc[2][3], 0, 0, 0);
        acc[3][3] = MFMA16(a3, bc3, acc[3][3], 0, 0, 0);
        bc0 = bn0; bc1 = bn1; bc2 = bn2; bc3 = bn3;
    }

    if (p < 2) {
        // Q/K: bounce each m-tile through wave-private LDS, then
        // coalesced copy to [tok][32] per head. (verified round 7)
        const float sc = (p == 0) ? 0.17677669529663687f : 1.0f;
        const int tl  = lane >> 2;            // local token 0..15
        const int cq  = lane & 3;             // col quarter
        const int head = 2 * wv + (cq >> 1);
        const int ch0  = (cq & 1) * 16;
        const size_t wh = (size_t)wid * 8 + head;
        unsigned short* dbase = qkv + wh * 6144 + (size_t)p * 2048 + ch0;
        #pragma unroll
        for (int m = 0; m < 4; ++m) {
            #pragma unroll
            for (int j = 0; j < 4; ++j)
                #pragma unroll
                for (int r = 0; r < 4; ++r)
                    sB[wv][lg * 4 + r][j * 16 + ln] = f2bf(acc[m][j][r] * sc);
            bf16x8 v0 = *reinterpret_cast<const bf16x8*>(&sB[wv][tl][cq * 16]);
            bf16x8 v1 = *reinterpret_cast<const bf16x8*>(&sB[wv][tl][cq * 16 + 8]);
            unsigned short* dst = dbase + (size_t)(m * 16 + tl) * 32;
            *reinterpret_cast<bf16x8*>(dst)     = v0;
            *reinterpret_cast<bf16x8*>(dst + 8) = v1;
        }
    } else {
        // V: direct transposed writes VT[ch][tok] (verified round 7)
        #pragma unroll
        for (int j = 0; j < 4; ++j) {
            const int head = 2 * wv + (j >> 1);
            const int ch   = (j & 1) * 16 + ln;
            const size_t wh = (size_t)wid * 8 + head;
            unsigned short* vbase = qkv + wh * 6144 + 4096 + (size_t)ch * 64;
            #pragma unroll
            for (int m = 0; m < 4; ++m) {
                ushort4 pv;
                pv.x = f2bf(acc[m][j][0]); pv.y = f2bf(acc[m][j][1]);
                pv.z = f2bf(acc[m][j][2]); pv.w = f2bf(acc[m][j][3]);
                *reinterpret_cast<ushort4*>(vbase + m * 16 + lg * 4) = pv;
            }
        }
    }
}

// =====================================================================
// attn6: grid 8192 (1 block per window-head), 256 thr (4 waves),
// wave = 16 queries. Q/K/VT read directly from ws (L2/L3-hot);
// V-fragments prefetched before softmax; O (bf16) bounced through
// the dead sP buffer and written IN-PLACE over the Q slot.
// Per-wave self-contained: wave reads only its own 16 Q rows before
// overwriting them. LDS 9216 B.
// =====================================================================
__global__ __launch_bounds__(256, 4)
void attn6(unsigned short* __restrict__ qkv,
           const float* __restrict__ bias_tab,
           unsigned short* /*unused*/)
{
    __shared__ __align__(16) unsigned short sP[4][16][72];

    const int tid  = threadIdx.x;
    const int lane = tid & 63;
    const int wv   = tid >> 6;
    const int ln   = lane & 15;
    const int lg   = lane >> 4;

    unsigned short* base = qkv + (size_t)blockIdx.x * 6144;
    const unsigned short* Kb  = base + 2048;
    const unsigned short* VTb = base + 4096;

    const int q = wv * 16 + ln;
    bf16x8 qf = *reinterpret_cast<const bf16x8*>(base + (size_t)q * 32 + lg * 8);

    // prefetch all V fragments (independent of softmax chain)
    bf16x8 vf[2][2];
    #pragma unroll
    for (int ks = 0; ks < 2; ++ks)
        #pragma unroll
        for (int nt = 0; nt < 2; ++nt)
            vf[ks][nt] = *reinterpret_cast<const bf16x8*>(
                VTb + (size_t)(nt * 16 + ln) * 64 + ks * 32 + lg * 8);

    f32x4 st[4];
    #pragma unroll
    for (int mt = 0; mt < 4; ++mt) {
        bf16x8 kf = *reinterpret_cast<const bf16x8*>(
            Kb + (size_t)(mt * 16 + ln) * 32 + lg * 8);
        st[mt] = MFMA16(kf, qf, (f32x4)(0.f), 0, 0, 0);
    }

    float sv[16];
    float mx = -3.0e38f;
    #pragma unroll
    for (int mt = 0; mt < 4; ++mt) {
        float4 bt = *reinterpret_cast<const float4*>(
            &bias_tab[q * 64 + mt * 16 + lg * 4]);
        float b4[4] = {bt.x, bt.y, bt.z, bt.w};
        #pragma unroll
        for (int r = 0; r < 4; ++r) {
            float s = st[mt][r] + b4[r];
            sv[mt * 4 + r] = s;
            mx = fmaxf(mx, s);
        }
    }
    mx = fmaxf(mx, __shfl_xor(mx, 16));
    mx = fmaxf(mx, __shfl_xor(mx, 32));
    float sum = 0.f;
    #pragma unroll
    for (int i = 0; i < 16; ++i) { sv[i] = __expf(sv[i] - mx); sum += sv[i]; }
    sum += __shfl_xor(sum, 16);
    sum += __shfl_xor(sum, 32);
    const float inv = 1.0f / sum;

    #pragma unroll
    for (int mt = 0; mt < 4; ++mt) {
        ushort4 pv;
        pv.x = f2bf(sv[mt * 4 + 0] * inv);
        pv.y = f2bf(sv[mt * 4 + 1] * inv);
        pv.z = f2bf(sv[mt * 4 + 2] * inv);
        pv.w = f2bf(sv[mt * 4 + 3] * inv);
        *reinterpret_cast<ushort4*>(&sP[wv][ln][mt * 16 + lg * 4]) = pv;
    }

    f32x4 o[2] = {(f32x4)(0.f), (f32x4)(0.f)};
    #pragma unroll
    for (int ks = 0; ks < 2; ++ks) {
        bf16x8 pf = *reinterpret_cast<const bf16x8*>(&sP[wv][ln][ks * 32 + lg * 8]);
        #pragma unroll
        for (int nt = 0; nt < 2; ++nt)
            o[nt] = MFMA16(pf, vf[ks][nt], o[nt], 0, 0, 0);
    }

    // O -> bf16 via sP bounce (P dead), then 16B stores over the Q slot
    #pragma unroll
    for (int nt = 0; nt < 2; ++nt)
        #pragma unroll
        for (int r = 0; r < 4; ++r)
            sP[wv][lg * 4 + r][nt * 16 + ln] = f2bf(o[nt][r]);
    const int tl = lane >> 2, cq = lane & 3;
    bf16x8 ov = *reinterpret_cast<const bf16x8*>(&sP[wv][tl][cq * 8]);
    *reinterpret_cast<bf16x8*>(base + (size_t)(wv * 16 + tl) * 32 + cq * 8) = ov;
}

// =====================================================================
// proj5: out = O_gather @ w_out + b_out -> d_out (f32).
// A staged by gathering bf16 O slots from ws (straight copy, no cvt);
// GEMM identical to proj4; no in-place hazard.
// Block bid covers global tokens bid*64..+63: blw=bid>>6, hrow=bid&63
// fixed; local r = wcol. grid 1024, 256 thr. LDS 33792 B.
// =====================================================================
__global__ __launch_bounds__(256, 3)
void proj5(const unsigned short* __restrict__ qkv,
           const unsigned short* __restrict__ woutT,
           const float* __restrict__ b_out,
           float* __restrict__ out)
{
    __shared__ __align__(16) unsigned short sA[64][264];

    const int tid  = threadIdx.x;
    const int lane = tid & 63;
    const int wv   = tid >> 6;
    const int ln   = lane & 15;
    const int lg   = lane >> 4;
    const size_t m0 = (size_t)blockIdx.x * 64;

    const int blw  = blockIdx.x >> 6;
    const int hrow = blockIdx.x & 63;
    const int whr  = hrow >> 3;
    const int irow = (hrow & 7) * 8;       // i = irow + (r&7)

    const unsigned short* b0 = woutT + (size_t)((wv +  0) * 16 + ln) * 256 + lg * 8;
    const unsigned short* b1 = woutT + (size_t)((wv +  4) * 16 + ln) * 256 + lg * 8;
    const unsigned short* b2 = woutT + (size_t)((wv +  8) * 16 + ln) * 256 + lg * 8;
    const unsigned short* b3 = woutT + (size_t)((wv + 12) * 16 + ln) * 256 + lg * 8;
    bf16x8 bc0 = *reinterpret_cast<const bf16x8*>(b0);
    bf16x8 bc1 = *reinterpret_cast<const bf16x8*>(b1);
    bf16x8 bc2 = *reinterpret_cast<const bf16x8*>(b2);
    bf16x8 bc3 = *reinterpret_cast<const bf16x8*>(b3);

    // stage A: gather O[wh][i][32] slices (straight bf16 copy)
    #pragma unroll
    for (int it = 0; it < 8; ++it) {
        int idx = tid + (it << 8);
        int r = idx >> 5, c8 = idx & 31;     // r = wcol, c8: h = c8>>2
        int h = c8 >> 2, chunk = c8 & 3;
        int wid = blw * 64 + whr * 8 + (r >> 3);
        const unsigned short* src =
            qkv + (size_t)(wid * 8 + h) * 6144 + (size_t)(irow + (r & 7)) * 32 + chunk * 8;
        *reinterpret_cast<bf16x8*>(&sA[r][c8 * 8]) =
            *reinterpret_cast<const bf16x8*>(src);
    }
    __syncthreads();

    f32x4 acc[4][4];
    #pragma unroll
    for (int m = 0; m < 4; ++m)
        #pragma unroll
        for (int j = 0; j < 4; ++j) acc[m][j] = (f32x4)(0.f);

    #pragma unroll
    for (int st = 0; st < 8; ++st) {
        const int ko = st * 32 + lg * 8;
        bf16x8 a0 = *reinterpret_cast<const bf16x8*>(&sA[     ln][ko]);
        bf16x8 a1 = *reinterpret_cast<const bf16x8*>(&sA[16 + ln][ko]);
        bf16x8 a2 = *reinterpret_cast<const bf16x8*>(&sA[32 + ln][ko]);
        bf16x8 a3 = *reinterpret_cast<const bf16x8*>(&sA[48 + ln][ko]);
        bf16x8 bn0 = bc0, bn1 = bc1, bn2 = bc2, bn3 = bc3;
        if (st < 7) {
            bn0 = *reinterpret_cast<const bf16x8*>(b0 + (st + 1) * 32);
            bn1 = *reinterpret_cast<const bf16x8*>(b1 + (st + 1) * 32);
            bn2 = *reinterpret_cast<const bf16x8*>(b2 + (st + 1) * 32);
            bn3 = *reinterpret_cast<const bf16x8*>(b3 + (st + 1) * 32);
        }
        acc[0][0] = MFMA16(a0, bc0, acc[0][0], 0, 0, 0);
        acc[1][0] = MFMA16(a1, bc0, acc[1][0], 0, 0, 0);
        acc[2][0] = MFMA16(a2, bc0, acc[2][0], 0, 0, 0);
        acc[3][0] = MFMA16(a3, bc0, acc[3][0], 0, 0, 0);
        acc[0][1] = MFMA16(a0, bc1, acc[0][1], 0, 0, 0);
        acc[1][1] = MFMA16(a1, bc1, acc[1][1], 0, 0, 0);
        acc[2][1] = MFMA16(a2, bc1, acc[2][1], 0, 0, 0);
        acc[3][1] = MFMA16(a3, bc1, acc[3][1], 0, 0, 0);
        acc[0][2] = MFMA16(a0, bc2, acc[0][2], 0, 0, 0);
        acc[1][2] = MFMA16(a1, bc2, acc[1][2], 0, 0, 0);
        acc[2][2] = MFMA16(a2, bc2, acc[2][2], 0, 0, 0);
        acc[3][2] = MFMA16(a3, bc2, acc[3][2], 0, 0, 0);
        acc[0][3] = MFMA16(a0, bc3, acc[0][3], 0, 0, 0);
        acc[1][3] = MFMA16(a1, bc3, acc[1][3], 0, 0, 0);
        acc[2][3] = MFMA16(a2, bc3, acc[2][3], 0, 0, 0);
        acc[3][3] = MFMA16(a3, bc3, acc[3][3], 0, 0, 0);
        bc0 = bn0; bc1 = bn1; bc2 = bn2; bc3 = bn3;
    }

    #pragma unroll
    for (int j = 0; j < 4; ++j) {
        int nt = wv + 4 * j;
        float bias = b_out[nt * 16 + ln];
        #pragma unroll
        for (int m = 0; m < 4; ++m)
            #pragma unroll
            for (int r = 0; r < 4; ++r)
                out[(m0 + m * 16 + lg * 4 + r) * 256 + nt * 16 + ln] =
                    acc[m][j][r] + bias;
    }
}

// =====================================================================
// Fallback (verified rounds 5-6) if ws < WS3_NEED: winattn4 + proj4.
// =====================================================================
__global__ __launch_bounds__(256, 3)
void winattn4(const float* __restrict__ x,
              const unsigned short* __restrict__ wqkvT,
              const float* __restrict__ bias_tab,
              float* __restrict__ out)
{
    __shared__ __align__(16) unsigned char smem[38912];
    typedef unsigned short (*arr264)[264];
    typedef unsigned short (*arr72)[72];
    typedef unsigned short (*arr40)[40];
    arr264 sX = reinterpret_cast<arr264>(smem);
    arr40 sQ  = reinterpret_cast<arr40>(smem);
    arr40 sK  = reinterpret_cast<arr40>(smem + 10240);
    arr72 sVT = reinterpret_cast<arr72>(smem + 20480);
    arr72 sP  = reinterpret_cast<arr72>(smem + 29696);

    const int tid  = threadIdx.x;
    const int lane = tid & 63;
    const int wv   = tid >> 6;
    const int ln   = lane & 15;
    const int lg   = lane >> 4;

    const int L   = ((blockIdx.x & 7) << 9) + (blockIdx.x >> 3);
    const int wid = L >> 2;
    const int h0  = (L & 3) << 1;
    const int blw = wid >> 6;
    const int whr = (wid >> 3) & 7;
    const int wwc = wid & 7;
    const int tok_base = blw * 4096 + whr * 512 + wwc * 8;

    const int hp_own = wv >> 1;
    const int hf_own = wv & 1;
    const unsigned short* bq = wqkvT +
        (size_t)((h0 + hp_own) * 32 + hf_own * 16 + ln) * 256 + lg * 8;
    const unsigned short* bk = bq + 256 * 256;
    const unsigned short* bv = bk + 256 * 256;
    bf16x8 bc0 = *reinterpret_cast<const bf16x8*>(bq);
    bf16x8 bc1 = *reinterpret_cast<const bf16x8*>(bk);
    bf16x8 bc2 = *reinterpret_cast<const bf16x8*>(bv);

    #pragma unroll
    for (int it = 0; it < 8; ++it) {
        int idx = tid + (it << 8);
        int row = idx >> 5, c8 = idx & 31;
        int tok = tok_base + ((row >> 3) << 6) + (row & 7);
        const float* p = x + (size_t)tok * 256 + c8 * 8;
        float4 a = *reinterpret_cast<const float4*>(p);
        float4 b = *reinterpret_cast<const float4*>(p + 4);
        *reinterpret_cast<bf16x8*>(&sX[row][c8 * 8]) = cvt8(a, b);
    }
    __syncthreads();

    f32x4 acc[4][3];
    #pragma unroll
    for (int m = 0; m < 4; ++m)
        #pragma unroll
        for (int t = 0; t < 3; ++t) acc[m][t] = (f32x4)(0.f);

    #pragma unroll
    for (int st = 0; st < 8; ++st) {
        const int ko = st * 32 + lg * 8;
        bf16x8 a0 = *reinterpret_cast<const bf16x8*>(&sX[     ln][ko]);
        bf16x8 a1 = *reinterpret_cast<const bf16x8*>(&sX[16 + ln][ko]);
        bf16x8 a2 = *reinterpret_cast<const bf16x8*>(&sX[32 + ln][ko]);
        bf16x8 a3 = *reinterpret_cast<const bf16x8*>(&sX[48 + ln][ko]);
        bf16x8 bn0 = bc0, bn1 = bc1, bn2 = bc2;
        if (st < 7) {
            bn0 = *reinterpret_cast<const bf16x8*>(bq + (st + 1) * 32);
            bn1 = *reinterpret_cast<const bf16x8*>(bk + (st + 1) * 32);
            bn2 = *reinterpret_cast<const bf16x8*>(bv + (st + 1) * 32);
        }
        acc[0][0] = MFMA16(a0, bc0, acc[0][0], 0, 0, 0);
        acc[1][0] = MFMA16(a1, bc0, acc[1][0], 0, 0, 0);
        acc[2][0] = MFMA16(a2, bc0, acc[2][0], 0, 0, 0);
        acc[3][0] = MFMA16(a3, bc0, acc[3][0], 0, 0, 0);
        acc[0][1] = MFMA16(a0, bc1, acc[0][1], 0, 0, 0);
        acc[1][1] = MFMA16(a1, bc1, acc[1][1], 0, 0, 0);
        acc[2][1] = MFMA16(a2, bc1, acc[2][1], 0, 0, 0);
        acc[3][1] = MFMA16(a3, bc1, acc[3][1], 0, 0, 0);
        acc[0][2] = MFMA16(a0, bc2, acc[0][2], 0, 0, 0);
        acc[1][2] = MFMA16(a1, bc2, acc[1][2], 0, 0, 0);
        acc[2][2] = MFMA16(a2, bc2, acc[2][2], 0, 0, 0);
        acc[3][2] = MFMA16(a3, bc2, acc[3][2], 0, 0, 0);
        bc0 = bn0; bc1 = bn1; bc2 = bn2;
    }
    __syncthreads();

    const float scale = 0.17677669529663687f;
    #pragma unroll
    for (int m = 0; m < 4; ++m) {
        #pragma unroll
        for (int r = 0; r < 4; ++r)
            sQ[hp_own * 64 + m * 16 + lg * 4 + r][hf_own * 16 + ln] =
                f2bf(acc[m][0][r] * scale);
        #pragma unroll
        for (int r = 0; r < 4; ++r)
            sK[hp_own * 64 + m * 16 + lg * 4 + r][hf_own * 16 + ln] =
                f2bf(acc[m][1][r]);
        ushort4 pv;
        pv.x = f2bf(acc[m][2][0]); pv.y = f2bf(acc[m][2][1]);
        pv.z = f2bf(acc[m][2][2]); pv.w = f2bf(acc[m][2][3]);
        *reinterpret_cast<ushort4*>(
            &sVT[hp_own * 32 + hf_own * 16 + ln][m * 16 + lg * 4]) = pv;
    }
    __syncthreads();

    const int q = wv * 16 + ln;
    #pragma unroll
    for (int hp = 0; hp < 2; ++hp) {
        bf16x8 qf = *reinterpret_cast<const bf16x8*>(&sQ[hp * 64 + q][lg * 8]);
        f32x4 st[4];
        #pragma unroll
        for (int mt = 0; mt < 4; ++mt) {
            bf16x8 kf = *reinterpret_cast<const bf16x8*>(
                &sK[hp * 64 + mt * 16 + ln][lg * 8]);
            st[mt] = MFMA16(kf, qf, (f32x4)(0.f), 0, 0, 0);
        }

        float sv[16];
        float mx = -3.0e38f;
        #pragma unroll
        for (int mt = 0; mt < 4; ++mt) {
            float4 bt = *reinterpret_cast<const float4*>(
                &bias_tab[q * 64 + mt * 16 + lg * 4]);
            float b4[4] = {bt.x, bt.y, bt.z, bt.w};
            #pragma unroll
            for (int r = 0; r < 4; ++r) {
                float s = st[mt][r] + b4[r];
                sv[mt * 4 + r] = s;
                mx = fmaxf(mx, s);
            }
        }
        mx = fmaxf(mx, __shfl_xor(mx, 16));
        mx = fmaxf(mx, __shfl_xor(mx, 32));
        float sum = 0.f;
        #pragma unroll
        for (int i = 0; i < 16; ++i) { sv[i] = __expf(sv[i] - mx); sum += sv[i]; }
        sum += __shfl_xor(sum, 16);
        sum += __shfl_xor(sum, 32);
        const float inv = 1.0f / sum;

        #pragma unroll
        for (int mt = 0; mt < 4; ++mt) {
            ushort4 pv;
            pv.x = f2bf(sv[mt * 4 + 0] * inv);
            pv.y = f2bf(sv[mt * 4 + 1] * inv);
            pv.z = f2bf(sv[mt * 4 + 2] * inv);
            pv.w = f2bf(sv[mt * 4 + 3] * inv);
            *reinterpret_cast<ushort4*>(&sP[wv * 16 + ln][mt * 16 + lg * 4]) = pv;
        }

        f32x4 o[2] = {(f32x4)(0.f), (f32x4)(0.f)};
        #pragma unroll
        for (int ks = 0; ks < 2; ++ks) {
            bf16x8 pf = *reinterpret_cast<const bf16x8*>(
                &sP[wv * 16 + ln][ks * 32 + lg * 8]);
            #pragma unroll
            for (int nt = 0; nt < 2; ++nt) {
                bf16x8 vf = *reinterpret_cast<const bf16x8*>(
                    &sVT[hp * 32 + nt * 16 + ln][ks * 32 + lg * 8]);
                o[nt] = MFMA16(pf, vf, o[nt], 0, 0, 0);
            }
        }

        #pragma unroll
        for (int nt = 0; nt < 2; ++nt) {
            #pragma unroll
            for (int r = 0; r < 4; ++r) {
                int qi  = wv * 16 + lg * 4 + r;
                int tok = tok_base + ((qi >> 3) << 6) + (qi & 7);
                out[(size_t)tok * 256 + (h0 + hp) * 32 + nt * 16 + ln] = o[nt][r];
            }
        }
    }
}

__global__ __launch_bounds__(256, 3)
void proj4(float* __restrict__ io,
           const unsigned short* __restrict__ woutT,
           const float* __restrict__ b_out)
{
    __shared__ __align__(16) unsigned short sA[64][264];

    const int tid  = threadIdx.x;
    const int lane = tid & 63;
    const int wv   = tid >> 6;
    const int ln   = lane & 15;
    const int lg   = lane >> 4;
    const size_t m0 = (size_t)blockIdx.x * 64;

    const unsigned short* b0 = woutT + (size_t)((wv +  0) * 16 + ln) * 256 + lg * 8;
    const unsigned short* b1 = woutT + (size_t)((wv +  4) * 16 + ln) * 256 + lg * 8;
    const unsigned short* b2 = woutT + (size_t)((wv +  8) * 16 + ln) * 256 + lg * 8;
    const unsigned short* b3 = woutT + (size_t)((wv + 12) * 16 + ln) * 256 + lg * 8;
    bf16x8 bc0 = *reinterpret_cast<const bf16x8*>(b0);
    bf16x8 bc1 = *reinterpret_cast<const bf16x8*>(b1);
    bf16x8 bc2 = *reinterpret_cast<const bf16x8*>(b2);
    bf16x8 bc3 = *reinterpret_cast<const bf16x8*>(b3);

    #pragma unroll
    for (int it = 0; it < 8; ++it) {
        int idx = tid + (it << 8);
        int row = idx >> 5, c8 = idx & 31;
        const float* p = io + (m0 + row) * 256 + c8 * 8;
        float4 a = *reinterpret_cast<const float4*>(p);
        float4 b = *reinterpret_cast<const float4*>(p + 4);
        *reinterpret_cast<bf16x8*>(&sA[row][c8 * 8]) = cvt8(a, b);
    }
    __syncthreads();

    f32x4 acc[4][4];
    #pragma unroll
    for (int m = 0; m < 4; ++m)
        #pragma unroll
        for (int j = 0; j < 4; ++j) acc[m][j] = (f32x4)(0.f);

    #pragma unroll
    for (int st = 0; st < 8; ++st) {
        const int ko = st * 32 + lg * 8;
        bf16x8 a0 = *reinterpret_cast<const bf16x8*>(&sA[     ln][ko]);
        bf16x8 a1 = *reinterpret_cast<const bf16x8*>(&sA[16 + ln][ko]);
        bf16x8 a2 = *reinterpret_cast<const bf16x8*>(&sA[32 + ln][ko]);
        bf16x8 a3 = *reinterpret_cast<const bf16x8*>(&sA[48 + ln][ko]);
        bf16x8 bn0 = bc0, bn1 = bc1, bn2 = bc2, bn3 = bc3;
        if (st < 7) {
            bn0 = *reinterpret_cast<const bf16x8*>(b0 + (st + 1) * 32);
            bn1 = *reinterpret_cast<const bf16x8*>(b1 + (st + 1) * 32);
            bn2 = *reinterpret_cast<const bf16x8*>(b2 + (st + 1) * 32);
            bn3 = *reinterpret_cast<const bf16x8*>(b3 + (st + 1) * 32);
        }
        acc[0][0] = MFMA16(a0, bc0, acc[0][0], 0, 0, 0);
        acc[1][0] = MFMA16(a1, bc0, acc[1][0], 0, 0, 0);
        acc[2][0] = MFMA16(a2, bc0, acc[2][0], 0, 0, 0);
        acc[3][0] = MFMA16(a3, bc0, acc[3][0], 0, 0, 0);
        acc[0][1] = MFMA16(a0, bc1, acc[0][1], 0, 0, 0);
        acc[1][1] = MFMA16(a1, bc1, acc[1][1], 0, 0, 0);
        acc[2][1] = MFMA16(a2, bc1, acc[2][1], 0, 0, 0);
        acc[3][1] = MFMA16(a3, bc1, acc[3][1], 0, 0, 0);
        acc[0][2] = MFMA16(a0, bc2, acc[0][2], 0, 0, 0);
        acc[1][2] = MFMA16(a1, bc2, acc[1][2], 0, 0, 0);
        acc[2][2] = MFMA16(a2, bc2, acc[2][2], 0, 0, 0);
        acc[3][2] = MFMA16(a3, bc2, acc[3][2], 0, 0, 0);
        acc[0][3] = MFMA16(a0, bc3, acc[0][3], 0, 0, 0);
        acc[1][3] = MFMA16(a1, bc3, acc[1][3], 0, 0, 0);
        acc[2][3] = MFMA16(a2, bc3, acc[2][3], 0, 0, 0);
        acc[3][3] = MFMA16(a3, bc3, acc[3][3], 0, 0, 0);
        bc0 = bn0; bc1 = bn1; bc2 = bn2; bc3 = bn3;
    }

    #pragma unroll
    for (int j = 0; j < 4; ++j) {
        int nt = wv + 4 * j;
        float bias = b_out[nt * 16 + ln];
        #pragma unroll
        for (int m = 0; m < 4; ++m)
            #pragma unroll
            for (int r = 0; r < 4; ++r)
                io[(m0 + m * 16 + lg * 4 + r) * 256 + nt * 16 + ln] =
                    acc[m][j][r] + bias;
    }
}

extern "C" void kernel_launch(void* const* d_in, const int* in_sizes, int n_in,
                              void* d_out, int out_size, void* d_ws, size_t ws_size,
                              hipStream_t stream) {
    const float* x     = (const float*)d_in[0];
    const float* w_qkv = (const float*)d_in[1];
    const float* w_out = (const float*)d_in[2];
    const float* b_out = (const float*)d_in[3];
    const float* pe    = (const float*)d_in[4];
    (void)in_sizes; (void)n_in; (void)out_size;

    float* out = (float*)d_out;
    unsigned short* wsT = (unsigned short*)d_ws;
    float* bias_tab = (float*)((char*)d_ws + 524288);

    prep_kernel<<<dim3(257), dim3(256), 0, stream>>>(w_qkv, w_out, pe, wsT, bias_tab);

    if (ws_size >= (size_t)WS3_NEED) {
        unsigned short* qkv = wsT + QKV_SHORT_OFF;
        qkv6 <<<dim3(3072), dim3(256), 0, stream>>>(x, wsT, qkv);
        attn6<<<dim3(8192), dim3(256), 0, stream>>>(qkv, bias_tab, nullptr);
        proj5<<<dim3(1024), dim3(256), 0, stream>>>(qkv, wsT + WOUTT_SHORT_OFF, b_out, out);
    } else {
        winattn4<<<dim3(4096), dim3(256), 0, stream>>>(x, wsT, bias_tab, out);
        proj4   <<<dim3(1024), dim3(256), 0, stream>>>(out, wsT + WOUTT_SHORT_OFF, b_out);
    }
}

// Round 9
// 117.341 us; speedup vs baseline: 1.3548x; 1.3548x over previous
//
#include <hip/hip_runtime.h>

typedef float f32x4 __attribute__((ext_vector_type(4)));
typedef short bf16x8 __attribute__((ext_vector_type(8)));

#define MFMA16 __builtin_amdgcn_mfma_f32_16x16x32_bf16

// ---------- bf16 helpers (manual RNE, verified rounds 2-8) ----------
__device__ __forceinline__ unsigned short f2bf(float f) {
    union { float f; unsigned int i; } x;
    x.f = f;
    unsigned int i = x.i;
    unsigned int lsb = (i >> 16) & 1u;
    i += 0x7FFFu + lsb;
    return (unsigned short)(i >> 16);
}
__device__ __forceinline__ bf16x8 cvt8(float4 a, float4 b) {
    union { bf16x8 v; unsigned short u[8]; } r;
    r.u[0] = f2bf(a.x); r.u[1] = f2bf(a.y); r.u[2] = f2bf(a.z); r.u[3] = f2bf(a.w);
    r.u[4] = f2bf(b.x); r.u[5] = f2bf(b.y); r.u[6] = f2bf(b.z); r.u[7] = f2bf(b.w);
    return r.v;
}

// ws layout (bytes):
//   0        : WqkvT bf16 [768][256]   (393216 B)
//   393216   : WoutT bf16 [256][256]   (131072 B)
//   524288   : bias_tab f32 [64][64]   (16384 B)
#define WS_NEED 540672
#define WOUTT_SHORT_OFF 196608

// =====================================================================
// Prep: transpose weights to bf16 n-major; expand PE to [q][j] table.
// =====================================================================
__global__ void prep_kernel(const float* __restrict__ wqkv,
                            const float* __restrict__ wout,
                            const float* __restrict__ pe,
                            unsigned short* __restrict__ wsT,
                            float* __restrict__ bias_tab)
{
    const int b = blockIdx.x, tid = threadIdx.x;
    if (b < 256) {
        const int w = tid >> 6, l = tid & 63;
        const int r = b * 4 + w;               // output row (n)
        const float* src;
        unsigned short* dst;
        int stride;
        if (r < 768) { src = wqkv + r; stride = 768; dst = wsT + (size_t)r * 256; }
        else { int n = r - 768; src = wout + n; stride = 256;
               dst = wsT + WOUTT_SHORT_OFF + (size_t)n * 256; }
        ushort4 v;
        v.x = f2bf(src[(size_t)(l * 4 + 0) * stride]);
        v.y = f2bf(src[(size_t)(l * 4 + 1) * stride]);
        v.z = f2bf(src[(size_t)(l * 4 + 2) * stride]);
        v.w = f2bf(src[(size_t)(l * 4 + 3) * stride]);
        *reinterpret_cast<ushort4*>(dst + l * 4) = v;
    } else {
        #pragma unroll
        for (int i = 0; i < 16; ++i) {
            int idx = tid + i * 256;           // q*64 + j
            int q = idx >> 6, j = idx & 63;
            int dy = (j >> 3) - (q >> 3) + 7;
            int dx = (j & 7) - (q & 7) + 7;
            bias_tab[idx] = pe[dy * 15 + dx];
        }
    }
}

// =====================================================================
// winattn5: round-5 winattn3 (verified 97us) + T14 async-split staging:
// chunk kc+1's X(f32) and W(bf16) global loads are issued into
// REGISTERS before chunk kc's MFMA phase; cvt+ds_write happen after the
// next barrier. Layouts, MFMA loop, epilogue, attention: verbatim
// winattn3. grid 4096 (2 heads/block), 256 thr. LDS 38912 B.
// =====================================================================
__global__ __launch_bounds__(256, 3)
void winattn5(const float* __restrict__ x,
              const unsigned short* __restrict__ wqkvT,
              const float* __restrict__ bias_tab,
              float* __restrict__ out)
{
    __shared__ __align__(16) unsigned char smem[38912];
    typedef unsigned short (*arr72)[72];
    typedef unsigned short (*arr40)[40];
    // GEMM-phase views
    arr72 sXc = reinterpret_cast<arr72>(smem);            // [64][72]
    arr72 sWc = reinterpret_cast<arr72>(smem + 9216);     // [192][72]
    // attn-phase views (alias; valid after post-GEMM barrier)
    arr40 sQ  = reinterpret_cast<arr40>(smem);            // [2*64][40]
    arr40 sK  = reinterpret_cast<arr40>(smem + 10240);    // [2*64][40]
    arr72 sVT = reinterpret_cast<arr72>(smem + 20480);    // [2*32][72]
    arr72 sP  = reinterpret_cast<arr72>(smem + 29696);    // [4*16][72]

    const int tid  = threadIdx.x;
    const int lane = tid & 63;
    const int wv   = tid >> 6;
    const int ln   = lane & 15;
    const int lg   = lane >> 4;

    // XCD swizzle: the 4 blocks of one window land on the same XCD
    const int L   = ((blockIdx.x & 7) << 9) + (blockIdx.x >> 3);
    const int wid = L >> 2;
    const int h0  = (L & 3) << 1;          // head pair h0, h0+1
    const int blw = wid >> 6;
    const int whr = (wid >> 3) & 7;
    const int wwc = wid & 7;
    const int tok_base = blw * 4096 + whr * 512 + wwc * 8;
    // token(i) = tok_base + (i>>3)*64 + (i&7)

    // ---- prefetch source pointers (same maps as winattn3 staging) ----
    const int c8 = tid & 7;                 // 8-elem column group
    const int xrow0 = tid >> 3;             // X rows: it0 -> 0..31
    const int xrow1 = 32 + (tid >> 3);      //         it1 -> 32..63
    const float* xs0 = x + (size_t)(tok_base + ((xrow0 >> 3) << 6) + (xrow0 & 7)) * 256 + c8 * 8;
    const float* xs1 = x + (size_t)(tok_base + ((xrow1 >> 3) << 6) + (xrow1 & 7)) * 256 + c8 * 8;
    // W rows: r = it*32 + (tid>>3), it = 0..5
    const int wrb = tid >> 3;
    const unsigned short* ws0; const unsigned short* ws1;
    const unsigned short* ws2; const unsigned short* ws3;
    const unsigned short* ws4; const unsigned short* ws5;
    {
        #define WSRC(IT) ({ int r = (IT)*32 + wrb; int g = r >> 5, sub = r & 31; \
            int n = (g >> 1) * 256 + (h0 + (g & 1)) * 32 + sub;                  \
            wqkvT + (size_t)n * 256 + c8 * 8; })
        ws0 = WSRC(0); ws1 = WSRC(1); ws2 = WSRC(2);
        ws3 = WSRC(3); ws4 = WSRC(4); ws5 = WSRC(5);
        #undef WSRC
    }

    // ---- prologue: load chunk 0 into registers ----
    float4 xa0 = *reinterpret_cast<const float4*>(xs0);
    float4 xb0 = *reinterpret_cast<const float4*>(xs0 + 4);
    float4 xa1 = *reinterpret_cast<const float4*>(xs1);
    float4 xb1 = *reinterpret_cast<const float4*>(xs1 + 4);
    bf16x8 w0 = *reinterpret_cast<const bf16x8*>(ws0);
    bf16x8 w1 = *reinterpret_cast<const bf16x8*>(ws1);
    bf16x8 w2 = *reinterpret_cast<const bf16x8*>(ws2);
    bf16x8 w3 = *reinterpret_cast<const bf16x8*>(ws3);
    bf16x8 w4 = *reinterpret_cast<const bf16x8*>(ws4);
    bf16x8 w5 = *reinterpret_cast<const bf16x8*>(ws5);

    f32x4 acc[12];
    #pragma unroll
    for (int i = 0; i < 12; ++i) acc[i] = (f32x4)(0.f);

    #pragma unroll
    for (int kc = 0; kc < 4; ++kc) {
        // ---- write phase: regs (chunk kc) -> LDS ----
        *reinterpret_cast<bf16x8*>(&sXc[xrow0][c8 * 8]) = cvt8(xa0, xb0);
        *reinterpret_cast<bf16x8*>(&sXc[xrow1][c8 * 8]) = cvt8(xa1, xb1);
        *reinterpret_cast<bf16x8*>(&sWc[0 * 32 + wrb][c8 * 8]) = w0;
        *reinterpret_cast<bf16x8*>(&sWc[1 * 32 + wrb][c8 * 8]) = w1;
        *reinterpret_cast<bf16x8*>(&sWc[2 * 32 + wrb][c8 * 8]) = w2;
        *reinterpret_cast<bf16x8*>(&sWc[3 * 32 + wrb][c8 * 8]) = w3;
        *reinterpret_cast<bf16x8*>(&sWc[4 * 32 + wrb][c8 * 8]) = w4;
        *reinterpret_cast<bf16x8*>(&sWc[5 * 32 + wrb][c8 * 8]) = w5;
        __syncthreads();                    // (A) writes visible

        // ---- issue chunk kc+1 loads (fly under the MFMAs below) ----
        if (kc < 3) {
            const int ko = (kc + 1) * 64;   // 64 elems per chunk
            xa0 = *reinterpret_cast<const float4*>(xs0 + ko);
            xb0 = *reinterpret_cast<const float4*>(xs0 + ko + 4);
            xa1 = *reinterpret_cast<const float4*>(xs1 + ko);
            xb1 = *reinterpret_cast<const float4*>(xs1 + ko + 4);
            w0 = *reinterpret_cast<const bf16x8*>(ws0 + ko);
            w1 = *reinterpret_cast<const bf16x8*>(ws1 + ko);
            w2 = *reinterpret_cast<const bf16x8*>(ws2 + ko);
            w3 = *reinterpret_cast<const bf16x8*>(ws3 + ko);
            w4 = *reinterpret_cast<const bf16x8*>(ws4 + ko);
            w5 = *reinterpret_cast<const bf16x8*>(ws5 + ko);
        }

        // ---- MFMA phase (verbatim winattn3) ----
        #pragma unroll
        for (int ks = 0; ks < 2; ++ks) {
            bf16x8 a = *reinterpret_cast<const bf16x8*>(
                &sXc[wv * 16 + ln][ks * 32 + lg * 8]);
            #pragma unroll
            for (int m = 0; m < 3; ++m)
                #pragma unroll
                for (int hp = 0; hp < 2; ++hp)
                    #pragma unroll
                    for (int hf = 0; hf < 2; ++hf) {
                        int r = (m * 2 + hp) * 32 + hf * 16 + ln;
                        bf16x8 b = *reinterpret_cast<const bf16x8*>(
                            &sWc[r][ks * 32 + lg * 8]);
                        acc[hp * 6 + m * 2 + hf] =
                            MFMA16(a, b, acc[hp * 6 + m * 2 + hf], 0, 0, 0);
                    }
        }
        __syncthreads();                    // (B) MFMA reads done
    }

    // ---- epilogue: Q(scaled),K -> [tok][ch]; V -> V^T[ch][tok] ----
    const float scale = 0.17677669529663687f;
    #pragma unroll
    for (int hp = 0; hp < 2; ++hp) {
        #pragma unroll
        for (int j = 0; j < 2; ++j)
            #pragma unroll
            for (int r = 0; r < 4; ++r)
                sQ[hp * 64 + wv * 16 + lg * 4 + r][j * 16 + ln] =
                    f2bf(acc[hp * 6 + j][r] * scale);
        #pragma unroll
        for (int j = 2; j < 4; ++j)
            #pragma unroll
            for (int r = 0; r < 4; ++r)
                sK[hp * 64 + wv * 16 + lg * 4 + r][(j - 2) * 16 + ln] =
                    f2bf(acc[hp * 6 + j][r]);
        #pragma unroll
        for (int j = 4; j < 6; ++j) {
            ushort4 pv;
            pv.x = f2bf(acc[hp * 6 + j][0]); pv.y = f2bf(acc[hp * 6 + j][1]);
            pv.z = f2bf(acc[hp * 6 + j][2]); pv.w = f2bf(acc[hp * 6 + j][3]);
            *reinterpret_cast<ushort4*>(
                &sVT[hp * 32 + (j - 4) * 16 + ln][wv * 16 + lg * 4]) = pv;
        }
    }
    __syncthreads();

    // ---- attention: wave wv owns q-rows 16wv..16wv+15, both heads ----
    const int q = wv * 16 + ln;
    #pragma unroll
    for (int hp = 0; hp < 2; ++hp) {
        bf16x8 qf = *reinterpret_cast<const bf16x8*>(&sQ[hp * 64 + q][lg * 8]);
        f32x4 st[4];
        #pragma unroll
        for (int mt = 0; mt < 4; ++mt) {
            bf16x8 kf = *reinterpret_cast<const bf16x8*>(
                &sK[hp * 64 + mt * 16 + ln][lg * 8]);
            st[mt] = MFMA16(kf, qf, (f32x4)(0.f), 0, 0, 0);
        }

        float sv[16];
        float mx = -3.0e38f;
        #pragma unroll
        for (int mt = 0; mt < 4; ++mt) {
            float4 bt = *reinterpret_cast<const float4*>(
                &bias_tab[q * 64 + mt * 16 + lg * 4]);
            float b4[4] = {bt.x, bt.y, bt.z, bt.w};
            #pragma unroll
            for (int r = 0; r < 4; ++r) {
                float s = st[mt][r] + b4[r];
                sv[mt * 4 + r] = s;
                mx = fmaxf(mx, s);
            }
        }
        mx = fmaxf(mx, __shfl_xor(mx, 16));
        mx = fmaxf(mx, __shfl_xor(mx, 32));
        float sum = 0.f;
        #pragma unroll
        for (int i = 0; i < 16; ++i) { sv[i] = __expf(sv[i] - mx); sum += sv[i]; }
        sum += __shfl_xor(sum, 16);
        sum += __shfl_xor(sum, 32);
        const float inv = 1.0f / sum;

        #pragma unroll
        for (int mt = 0; mt < 4; ++mt) {
            ushort4 pv;
            pv.x = f2bf(sv[mt * 4 + 0] * inv);
            pv.y = f2bf(sv[mt * 4 + 1] * inv);
            pv.z = f2bf(sv[mt * 4 + 2] * inv);
            pv.w = f2bf(sv[mt * 4 + 3] * inv);
            *reinterpret_cast<ushort4*>(&sP[wv * 16 + ln][mt * 16 + lg * 4]) = pv;
        }

        f32x4 o[2] = {(f32x4)(0.f), (f32x4)(0.f)};
        #pragma unroll
        for (int ks = 0; ks < 2; ++ks) {
            bf16x8 pf = *reinterpret_cast<const bf16x8*>(
                &sP[wv * 16 + ln][ks * 32 + lg * 8]);
            #pragma unroll
            for (int nt = 0; nt < 2; ++nt) {
                bf16x8 vf = *reinterpret_cast<const bf16x8*>(
                    &sVT[hp * 32 + nt * 16 + ln][ks * 32 + lg * 8]);
                o[nt] = MFMA16(pf, vf, o[nt], 0, 0, 0);
            }
        }

        #pragma unroll
        for (int nt = 0; nt < 2; ++nt) {
            #pragma unroll
            for (int r = 0; r < 4; ++r) {
                int qi  = wv * 16 + lg * 4 + r;
                int tok = tok_base + ((qi >> 3) << 6) + (qi & 7);
                out[(size_t)tok * 256 + (h0 + hp) * 32 + nt * 16 + ln] = o[nt][r];
            }
        }
    }
}

// =====================================================================
// proj4: in-place out = A @ w_out + b_out (verified round 6, ~16us).
// =====================================================================
__global__ __launch_bounds__(256, 3)
void proj4(float* __restrict__ io,
           const unsigned short* __restrict__ woutT,
           const float* __restrict__ b_out)
{
    __shared__ __align__(16) unsigned short sA[64][264];

    const int tid  = threadIdx.x;
    const int lane = tid & 63;
    const int wv   = tid >> 6;
    const int ln   = lane & 15;
    const int lg   = lane >> 4;
    const size_t m0 = (size_t)blockIdx.x * 64;

    const unsigned short* b0 = woutT + (size_t)((wv +  0) * 16 + ln) * 256 + lg * 8;
    const unsigned short* b1 = woutT + (size_t)((wv +  4) * 16 + ln) * 256 + lg * 8;
    const unsigned short* b2 = woutT + (size_t)((wv +  8) * 16 + ln) * 256 + lg * 8;
    const unsigned short* b3 = woutT + (size_t)((wv + 12) * 16 + ln) * 256 + lg * 8;
    bf16x8 bc0 = *reinterpret_cast<const bf16x8*>(b0);
    bf16x8 bc1 = *reinterpret_cast<const bf16x8*>(b1);
    bf16x8 bc2 = *reinterpret_cast<const bf16x8*>(b2);
    bf16x8 bc3 = *reinterpret_cast<const bf16x8*>(b3);

    #pragma unroll
    for (int it = 0; it < 8; ++it) {
        int idx = tid + (it << 8);
        int row = idx >> 5, c8 = idx & 31;
        const float* p = io + (m0 + row) * 256 + c8 * 8;
        float4 a = *reinterpret_cast<const float4*>(p);
        float4 b = *reinterpret_cast<const float4*>(p + 4);
        *reinterpret_cast<bf16x8*>(&sA[row][c8 * 8]) = cvt8(a, b);
    }
    __syncthreads();

    f32x4 acc[4][4];
    #pragma unroll
    for (int m = 0; m < 4; ++m)
        #pragma unroll
        for (int j = 0; j < 4; ++j) acc[m][j] = (f32x4)(0.f);

    #pragma unroll
    for (int st = 0; st < 8; ++st) {
        const int ko = st * 32 + lg * 8;
        bf16x8 a0 = *reinterpret_cast<const bf16x8*>(&sA[     ln][ko]);
        bf16x8 a1 = *reinterpret_cast<const bf16x8*>(&sA[16 + ln][ko]);
        bf16x8 a2 = *reinterpret_cast<const bf16x8*>(&sA[32 + ln][ko]);
        bf16x8 a3 = *reinterpret_cast<const bf16x8*>(&sA[48 + ln][ko]);
        bf16x8 bn0 = bc0, bn1 = bc1, bn2 = bc2, bn3 = bc3;
        if (st < 7) {
            bn0 = *reinterpret_cast<const bf16x8*>(b0 + (st + 1) * 32);
            bn1 = *reinterpret_cast<const bf16x8*>(b1 + (st + 1) * 32);
            bn2 = *reinterpret_cast<const bf16x8*>(b2 + (st + 1) * 32);
            bn3 = *reinterpret_cast<const bf16x8*>(b3 + (st + 1) * 32);
        }
        acc[0][0] = MFMA16(a0, bc0, acc[0][0], 0, 0, 0);
        acc[1][0] = MFMA16(a1, bc0, acc[1][0], 0, 0, 0);
        acc[2][0] = MFMA16(a2, bc0, acc[2][0], 0, 0, 0);
        acc[3][0] = MFMA16(a3, bc0, acc[3][0], 0, 0, 0);
        acc[0][1] = MFMA16(a0, bc1, acc[0][1], 0, 0, 0);
        acc[1][1] = MFMA16(a1, bc1, acc[1][1], 0, 0, 0);
        acc[2][1] = MFMA16(a2, bc1, acc[2][1], 0, 0, 0);
        acc[3][1] = MFMA16(a3, bc1, acc[3][1], 0, 0, 0);
        acc[0][2] = MFMA16(a0, bc2, acc[0][2], 0, 0, 0);
        acc[1][2] = MFMA16(a1, bc2, acc[1][2], 0, 0, 0);
        acc[2][2] = MFMA16(a2, bc2, acc[2][2], 0, 0, 0);
        acc[3][2] = MFMA16(a3, bc2, acc[3][2], 0, 0, 0);
        acc[0][3] = MFMA16(a0, bc3, acc[0][3], 0, 0, 0);
        acc[1][3] = MFMA16(a1, bc3, acc[1][3], 0, 0, 0);
        acc[2][3] = MFMA16(a2, bc3, acc[2][3], 0, 0, 0);
        acc[3][3] = MFMA16(a3, bc3, acc[3][3], 0, 0, 0);
        bc0 = bn0; bc1 = bn1; bc2 = bn2; bc3 = bn3;
    }

    #pragma unroll
    for (int j = 0; j < 4; ++j) {
        int nt = wv + 4 * j;
        float bias = b_out[nt * 16 + ln];
        #pragma unroll
        for (int m = 0; m < 4; ++m)
            #pragma unroll
            for (int r = 0; r < 4; ++r)
                io[(m0 + m * 16 + lg * 4 + r) * 256 + nt * 16 + ln] =
                    acc[m][j][r] + bias;
    }
}

// =====================================================================
// Fallback (round-3 verified kernels) if ws_size < WS_NEED.
// =====================================================================
__device__ __forceinline__ bf16x8 ldsFrag(const unsigned short* p) {
    return *reinterpret_cast<const bf16x8*>(p);
}

__global__ __launch_bounds__(256, 2)
void winattn_fb(const float* __restrict__ x,
                const float* __restrict__ w_qkv,
                const float* __restrict__ pe,
                float* __restrict__ attn_out)
{
    __shared__ __align__(16) unsigned short sX[64][264];
    __shared__ __align__(16) unsigned short sW[96][72];
    __shared__ __align__(16) unsigned short sQ[64][40];
    __shared__ __align__(16) unsigned short sK[64][40];
    __shared__ __align__(16) unsigned short sVT[32][72];
    __shared__ float sPE[225];
    unsigned short* sP = &sX[0][0];

    const int tid  = threadIdx.x;
    const int lane = tid & 63;
    const int wv   = tid >> 6;
    const int ln   = lane & 15;
    const int lg   = lane >> 4;

    const int h   = blockIdx.x & 7;
    const int wid = blockIdx.x >> 3;
    const int blw = wid >> 6;
    const int whr = (wid >> 3) & 7;
    const int wwc = wid & 7;
    const int tok_base = blw * 4096 + whr * 512 + wwc * 8;

    if (tid < 225) sPE[tid] = pe[tid];

    #pragma unroll
    for (int it = 0; it < 16; ++it) {
        int g = tid + (it << 8);
        int row = g >> 6, f4 = g & 63;
        int tok = tok_base + ((row >> 3) << 6) + (row & 7);
        float4 v = *reinterpret_cast<const float4*>(x + (size_t)tok * 256 + f4 * 4);
        ushort4 u;
        u.x = f2bf(v.x); u.y = f2bf(v.y); u.z = f2bf(v.z); u.w = f2bf(v.w);
        *reinterpret_cast<ushort4*>(&sX[row][f4 << 2]) = u;
    }

    auto stage_w = [&](int kc) {
        #pragma unroll
        for (int it = 0; it < 8; ++it) {
            int g = tid + (it << 8);
            int k = g >> 5, c = g & 31;
            if (c < 24) {
                int m = c >> 3, f4 = c & 7;
                float4 v = *reinterpret_cast<const float4*>(
                    w_qkv + (size_t)(kc * 64 + k) * 768 + m * 256 + h * 32 + f4 * 4);
                float vals[4] = {v.x, v.y, v.z, v.w};
                int n0 = m * 32 + f4 * 4;
                #pragma unroll
                for (int e0 = 0; e0 < 4; ++e0) {
                    int e = (e0 + lane) & 3;
                    sW[n0 + e][k] = f2bf(vals[e]);
                }
            }
        }
    };

    stage_w(0);
    __syncthreads();

    f32x4 acc[6];
    #pragma unroll
    for (int nt = 0; nt < 6; ++nt) acc[nt] = (f32x4)(0.f);

    for (int kc = 0; kc < 4; ++kc) {
        #pragma unroll
        for (int ks = 0; ks < 2; ++ks) {
            bf16x8 a = ldsFrag(&sX[wv * 16 + ln][kc * 64 + ks * 32 + lg * 8]);
            #pragma unroll
            for (int nt = 0; nt < 6; ++nt) {
                bf16x8 b = ldsFrag(&sW[nt * 16 + ln][ks * 32 + lg * 8]);
                acc[nt] = MFMA16(a, b, acc[nt], 0, 0, 0);
            }
        }
        if (kc < 3) { __syncthreads(); stage_w(kc + 1); __syncthreads(); }
    }

    #pragma unroll
    for (int nt = 0; nt < 4; ++nt)
        #pragma unroll
        for (int r = 0; r < 4; ++r) {
            int row = wv * 16 + lg * 4 + r;
            unsigned short bv = f2bf(acc[nt][r]);
            if (nt < 2) sQ[row][nt * 16 + ln] = bv;
            else        sK[row][(nt - 2) * 16 + ln] = bv;
        }
    #pragma unroll
    for (int nt = 4; nt < 6; ++nt) {
        ushort4 pv;
        pv.x = f2bf(acc[nt][0]); pv.y = f2bf(acc[nt][1]);
        pv.z = f2bf(acc[nt][2]); pv.w = f2bf(acc[nt][3]);
        *reinterpret_cast<ushort4*>(&sVT[(nt - 4) * 16 + ln][wv * 16 + lg * 4]) = pv;
    }
    __syncthreads();

    const f32x4 zero = (f32x4)(0.f);
    bf16x8 qf = ldsFrag(&sQ[wv * 16 + ln][lg * 8]);
    f32x4 st[4];
    #pragma unroll
    for (int mt = 0; mt < 4; ++mt) {
        bf16x8 kf = ldsFrag(&sK[mt * 16 + ln][lg * 8]);
        st[mt] = MFMA16(kf, qf, zero, 0, 0, 0);
    }

    const int q = wv * 16 + ln;
    const int qr = q >> 3, qc = q & 7;
    const float scale = 0.17677669529663687f;
    float sv[16];
    float mx = -3.0e38f;
    #pragma unroll
    for (int mt = 0; mt < 4; ++mt)
        #pragma unroll
        for (int r = 0; r < 4; ++r) {
            int j = mt * 16 + lg * 4 + r;
            int dy = (j >> 3) - qr + 7;
            int dx = (j & 7) - qc + 7;
            float s = st[mt][r] * scale + sPE[dy * 15 + dx];
            sv[mt * 4 + r] = s;
            mx = fmaxf(mx, s);
        }
    mx = fmaxf(mx, __shfl_xor(mx, 16));
    mx = fmaxf(mx, __shfl_xor(mx, 32));
    float sum = 0.f;
    #pragma unroll
    for (int i = 0; i < 16; ++i) { sv[i] = __expf(sv[i] - mx); sum += sv[i]; }
    sum += __shfl_xor(sum, 16);
    sum += __shfl_xor(sum, 32);
    const float inv = 1.0f / sum;

    unsigned short* sPw = sP + wv * (16 * 72) + ln * 72;
    #pragma unroll
    for (int mt = 0; mt < 4; ++mt) {
        ushort4 pv;
        pv.x = f2bf(sv[mt * 4 + 0] * inv);
        pv.y = f2bf(sv[mt * 4 + 1] * inv);
        pv.z = f2bf(sv[mt * 4 + 2] * inv);
        pv.w = f2bf(sv[mt * 4 + 3] * inv);
        *reinterpret_cast<ushort4*>(sPw + mt * 16 + lg * 4) = pv;
    }

    f32x4 o[2] = {zero, zero};
    #pragma unroll
    for (int ks = 0; ks < 2; ++ks) {
        bf16x8 pf = ldsFrag(sPw + ks * 32 + lg * 8);
        #pragma unroll
        for (int nt = 0; nt < 2; ++nt) {
            bf16x8 vf = ldsFrag(&sVT[nt * 16 + ln][ks * 32 + lg * 8]);
            o[nt] = MFMA16(pf, vf, o[nt], 0, 0, 0);
        }
    }
    #pragma unroll
    for (int nt = 0; nt < 2; ++nt)
        #pragma unroll
        for (int r = 0; r < 4; ++r) {
            int qi = wv * 16 + lg * 4 + r;
            int tok = tok_base + ((qi >> 3) << 6) + (qi & 7);
            attn_out[(size_t)tok * 256 + h * 32 + nt * 16 + ln] = o[nt][r];
        }
}

__global__ __launch_bounds__(256, 3)
void proj_fb(float* __restrict__ io,
             const float* __restrict__ w_out,
             const float* __restrict__ b_out)
{
    __shared__ __align__(16) unsigned short sA[64][72];
    __shared__ __align__(16) unsigned short sW2[256][72];
    __shared__ float sB[256];

    const int tid  = threadIdx.x;
    const int lane = tid & 63;
    const int wv   = tid >> 6;
    const int ln   = lane & 15;
    const int lg   = lane >> 4;
    const size_t m0 = (size_t)blockIdx.x * 64;

    sB[tid] = b_out[tid];

    f32x4 acc[16];
    #pragma unroll
    for (int nt = 0; nt < 16; ++nt) acc[nt] = (f32x4)(0.f);

    for (int kc = 0; kc < 4; ++kc) {
        if (kc) __syncthreads();
        #pragma unroll
        for (int it = 0; it < 4; ++it) {
            int g = tid + (it << 8);
            int row = g >> 4, f4 = g & 15;
            float4 v = *reinterpret_cast<const float4*>(
                io + (m0 + row) * 256 + kc * 64 + f4 * 4);
            ushort4 u;
            u.x = f2bf(v.x); u.y = f2bf(v.y); u.z = f2bf(v.z); u.w = f2bf(v.w);
            *reinterpret_cast<ushort4*>(&sA[row][f4 << 2]) = u;
        }
        #pragma unroll
        for (int i = 0; i < 16; ++i) {
            int f4 = ln + 16 * (i & 3);
            int kl = 16 * wv + lg + 4 * (i >> 2);
            float4 v = *reinterpret_cast<const float4*>(
                w_out + (size_t)(kc * 64 + kl) * 256 + f4 * 4);
            float vals[4] = {v.x, v.y, v.z, v.w};
            #pragma unroll
            for (int e0 = 0; e0 < 4; ++e0) {
                int e = (e0 + lane) & 3;
                sW2[f4 * 4 + e][kl] = f2bf(vals[e]);
            }
        }
        __syncthreads();

        #pragma unroll
        for (int ks = 0; ks < 2; ++ks) {
            bf16x8 a = ldsFrag(&sA[wv * 16 + ln][ks * 32 + lg * 8]);
            #pragma unroll
            for (int nt = 0; nt < 16; ++nt) {
                bf16x8 b = ldsFrag(&sW2[nt * 16 + ln][ks * 32 + lg * 8]);
                acc[nt] = MFMA16(a, b, acc[nt], 0, 0, 0);
            }
        }
    }

    #pragma unroll
    for (int nt = 0; nt < 16; ++nt) {
        float bias = sB[nt * 16 + ln];
        #pragma unroll
        for (int r = 0; r < 4; ++r) {
            int row = wv * 16 + lg * 4 + r;
            io[(m0 + row) * 256 + nt * 16 + ln] = acc[nt][r] + bias;
        }
    }
}

extern "C" void kernel_launch(void* const* d_in, const int* in_sizes, int n_in,
                              void* d_out, int out_size, void* d_ws, size_t ws_size,
                              hipStream_t stream) {
    const float* x     = (const float*)d_in[0];
    const float* w_qkv = (const float*)d_in[1];
    const float* w_out = (const float*)d_in[2];
    const float* b_out = (const float*)d_in[3];
    const float* pe    = (const float*)d_in[4];
    (void)in_sizes; (void)n_in; (void)out_size;

    float* out = (float*)d_out;

    if (ws_size >= (size_t)WS_NEED) {
        unsigned short* wsT = (unsigned short*)d_ws;
        float* bias_tab = (float*)((char*)d_ws + 524288);
        prep_kernel<<<dim3(257),  dim3(256), 0, stream>>>(w_qkv, w_out, pe, wsT, bias_tab);
        winattn5   <<<dim3(4096), dim3(256), 0, stream>>>(x, wsT, bias_tab, out);
        proj4      <<<dim3(1024), dim3(256), 0, stream>>>(out, wsT + WOUTT_SHORT_OFF, b_out);
    } else {
        winattn_fb <<<dim3(8192), dim3(256), 0, stream>>>(x, w_qkv, pe, out);
        proj_fb    <<<dim3(1024), dim3(256), 0, stream>>>(out, w_out, b_out);
    }
}

// Round 10
// 116.749 us; speedup vs baseline: 1.3617x; 1.0051x over previous
//
#include <hip/hip_runtime.h>

typedef float f32x4 __attribute__((ext_vector_type(4)));
typedef short bf16x8 __attribute__((ext_vector_type(8)));

#define MFMA16 __builtin_amdgcn_mfma_f32_16x16x32_bf16

// ---------- bf16 helpers (manual RNE, verified rounds 2-9) ----------
__device__ __forceinline__ unsigned short f2bf(float f) {
    union { float f; unsigned int i; } x;
    x.f = f;
    unsigned int i = x.i;
    unsigned int lsb = (i >> 16) & 1u;
    i += 0x7FFFu + lsb;
    return (unsigned short)(i >> 16);
}
__device__ __forceinline__ bf16x8 cvt8(float4 a, float4 b) {
    union { bf16x8 v; unsigned short u[8]; } r;
    r.u[0] = f2bf(a.x); r.u[1] = f2bf(a.y); r.u[2] = f2bf(a.z); r.u[3] = f2bf(a.w);
    r.u[4] = f2bf(b.x); r.u[5] = f2bf(b.y); r.u[6] = f2bf(b.z); r.u[7] = f2bf(b.w);
    return r.v;
}
// XOR-16B-slot swizzle for 128B-row tiles (write & read use the same map)
__device__ __forceinline__ int swz(int row, int byteoff) {
    return row * 128 + ((((byteoff >> 4) ^ (row & 7)) << 4) | (byteoff & 15));
}

// ws layout (bytes):
//   0        : WqkvT bf16 [768][256]   (393216 B)
//   393216   : WoutT bf16 [256][256]   (131072 B)
//   524288   : bias_tab f32 [64][64]   (16384 B)
#define WS_NEED 540672
#define WOUTT_SHORT_OFF 196608

// =====================================================================
// Prep: transpose weights to bf16 n-major; expand PE to [q][j] table.
// =====================================================================
__global__ void prep_kernel(const float* __restrict__ wqkv,
                            const float* __restrict__ wout,
                            const float* __restrict__ pe,
                            unsigned short* __restrict__ wsT,
                            float* __restrict__ bias_tab)
{
    const int b = blockIdx.x, tid = threadIdx.x;
    if (b < 256) {
        const int w = tid >> 6, l = tid & 63;
        const int r = b * 4 + w;               // output row (n)
        const float* src;
        unsigned short* dst;
        int stride;
        if (r < 768) { src = wqkv + r; stride = 768; dst = wsT + (size_t)r * 256; }
        else { int n = r - 768; src = wout + n; stride = 256;
               dst = wsT + WOUTT_SHORT_OFF + (size_t)n * 256; }
        ushort4 v;
        v.x = f2bf(src[(size_t)(l * 4 + 0) * stride]);
        v.y = f2bf(src[(size_t)(l * 4 + 1) * stride]);
        v.z = f2bf(src[(size_t)(l * 4 + 2) * stride]);
        v.w = f2bf(src[(size_t)(l * 4 + 3) * stride]);
        *reinterpret_cast<ushort4*>(dst + l * 4) = v;
    } else {
        #pragma unroll
        for (int i = 0; i < 16; ++i) {
            int idx = tid + i * 256;           // q*64 + j
            int q = idx >> 6, j = idx & 63;
            int dy = (j >> 3) - (q >> 3) + 7;
            int dx = (j & 7) - (q & 7) + 7;
            bias_tab[idx] = pe[dy * 15 + dx];
        }
    }
}

// =====================================================================
// winattn6 = winattn5 + (1) m/n ownership swap in the QKV GEMM
// (wave owns ALL 64 rows x 3 n-tiles; B reg-reused x4; GEMM LDS reads
// 416->224 KB/block) + (2) XOR-16B-slot swizzled 128B-row tiles for
// X/W/VT/P (conflict flattening) + (3) LDS 36.9 KB -> 4 blocks/CU.
// T14 async-split staging, attention core, epilogue scatter: verified.
// grid 4096 (2 heads/block), 256 thr.
// =====================================================================
__global__ __launch_bounds__(256, 4)
void winattn6(const float* __restrict__ x,
              const unsigned short* __restrict__ wqkvT,
              const float* __restrict__ bias_tab,
              float* __restrict__ out)
{
    __shared__ __align__(16) unsigned char smem[36864];
    typedef unsigned short (*arr40)[40];
    // GEMM-phase views (swizzled 128B rows)
    unsigned char* Xb = smem;                               // [64][128B]
    unsigned char* Wb = smem + 8192;                        // [192][128B]
    // attn-phase views (alias; valid after post-GEMM barrier)
    arr40 sQ = reinterpret_cast<arr40>(smem);               // [128][40]
    arr40 sK = reinterpret_cast<arr40>(smem + 10240);       // [128][40]
    unsigned char* Vb = smem + 20480;                       // [64][128B] swz
    unsigned char* Pb = smem + 28672;                       // [64][128B] swz

    const int tid  = threadIdx.x;
    const int lane = tid & 63;
    const int wv   = tid >> 6;
    const int ln   = lane & 15;
    const int lg   = lane >> 4;

    // XCD swizzle: the 4 blocks of one window land on the same XCD
    const int L   = ((blockIdx.x & 7) << 9) + (blockIdx.x >> 3);
    const int wid = L >> 2;
    const int h0  = (L & 3) << 1;          // head pair h0, h0+1
    const int blw = wid >> 6;
    const int whr = (wid >> 3) & 7;
    const int wwc = wid & 7;
    const int tok_base = blw * 4096 + whr * 512 + wwc * 8;
    // token(i) = tok_base + (i>>3)*64 + (i&7)

    // ---- staging thread maps (T14 async-split, verified round 9) ----
    const int c8    = tid & 7;             // 16B slot within row
    const int xrow0 = tid >> 3;            // X rows 0..31
    const int xrow1 = 32 + (tid >> 3);     //        32..63
    const float* xs0 = x + (size_t)(tok_base + ((xrow0 >> 3) << 6) + (xrow0 & 7)) * 256 + c8 * 8;
    const float* xs1 = x + (size_t)(tok_base + ((xrow1 >> 3) << 6) + (xrow1 & 7)) * 256 + c8 * 8;
    // W rows r = it*32 + wrb; LDS row r = n-tile (r>>4) slot (r&15);
    // n-tile n_t -> W^T row n = m*256 + (h0+hp)*32 + hf*16 + (r&15)
    const int wrb = tid >> 3;
    const unsigned short* ws0; const unsigned short* ws1;
    const unsigned short* ws2; const unsigned short* ws3;
    const unsigned short* ws4; const unsigned short* ws5;
    {
        #define WSRC(IT) ({ int r = (IT)*32 + wrb; int nt_ = r >> 4;          \
            int m_ = nt_ >> 2, hp_ = (nt_ >> 1) & 1, hf_ = nt_ & 1;           \
            int n = m_ * 256 + (h0 + hp_) * 32 + hf_ * 16 + (r & 15);         \
            wqkvT + (size_t)n * 256 + c8 * 8; })
        ws0 = WSRC(0); ws1 = WSRC(1); ws2 = WSRC(2);
        ws3 = WSRC(3); ws4 = WSRC(4); ws5 = WSRC(5);
        #undef WSRC
    }

    // ---- prologue: load chunk 0 into registers ----
    float4 xa0 = *reinterpret_cast<const float4*>(xs0);
    float4 xb0 = *reinterpret_cast<const float4*>(xs0 + 4);
    float4 xa1 = *reinterpret_cast<const float4*>(xs1);
    float4 xb1 = *reinterpret_cast<const float4*>(xs1 + 4);
    bf16x8 w0 = *reinterpret_cast<const bf16x8*>(ws0);
    bf16x8 w1 = *reinterpret_cast<const bf16x8*>(ws1);
    bf16x8 w2 = *reinterpret_cast<const bf16x8*>(ws2);
    bf16x8 w3 = *reinterpret_cast<const bf16x8*>(ws3);
    bf16x8 w4 = *reinterpret_cast<const bf16x8*>(ws4);
    bf16x8 w5 = *reinterpret_cast<const bf16x8*>(ws5);

    f32x4 acc[4][3];
    #pragma unroll
    for (int mt = 0; mt < 4; ++mt)
        #pragma unroll
        for (int jt = 0; jt < 3; ++jt) acc[mt][jt] = (f32x4)(0.f);

    #pragma unroll
    for (int kc = 0; kc < 4; ++kc) {
        // ---- write phase: regs (chunk kc) -> swizzled LDS ----
        *reinterpret_cast<bf16x8*>(Xb + swz(xrow0, c8 * 16)) = cvt8(xa0, xb0);
        *reinterpret_cast<bf16x8*>(Xb + swz(xrow1, c8 * 16)) = cvt8(xa1, xb1);
        *reinterpret_cast<bf16x8*>(Wb + swz(0 * 32 + wrb, c8 * 16)) = w0;
        *reinterpret_cast<bf16x8*>(Wb + swz(1 * 32 + wrb, c8 * 16)) = w1;
        *reinterpret_cast<bf16x8*>(Wb + swz(2 * 32 + wrb, c8 * 16)) = w2;
        *reinterpret_cast<bf16x8*>(Wb + swz(3 * 32 + wrb, c8 * 16)) = w3;
        *reinterpret_cast<bf16x8*>(Wb + swz(4 * 32 + wrb, c8 * 16)) = w4;
        *reinterpret_cast<bf16x8*>(Wb + swz(5 * 32 + wrb, c8 * 16)) = w5;
        __syncthreads();                    // (A) writes visible

        // ---- issue chunk kc+1 loads (fly under the MFMAs below) ----
        if (kc < 3) {
            const int ko = (kc + 1) * 64;
            xa0 = *reinterpret_cast<const float4*>(xs0 + ko);
            xb0 = *reinterpret_cast<const float4*>(xs0 + ko + 4);
            xa1 = *reinterpret_cast<const float4*>(xs1 + ko);
            xb1 = *reinterpret_cast<const float4*>(xs1 + ko + 4);
            w0 = *reinterpret_cast<const bf16x8*>(ws0 + ko);
            w1 = *reinterpret_cast<const bf16x8*>(ws1 + ko);
            w2 = *reinterpret_cast<const bf16x8*>(ws2 + ko);
            w3 = *reinterpret_cast<const bf16x8*>(ws3 + ko);
            w4 = *reinterpret_cast<const bf16x8*>(ws4 + ko);
            w5 = *reinterpret_cast<const bf16x8*>(ws5 + ko);
        }

        // ---- MFMA phase: wave owns all 4 m-tiles x its 3 n-tiles ----
        #pragma unroll
        for (int ks = 0; ks < 2; ++ks) {
            const int cb = ks * 64 + lg * 16;   // byte col within row
            bf16x8 a0 = *reinterpret_cast<const bf16x8*>(Xb + swz(     ln, cb));
            bf16x8 a1 = *reinterpret_cast<const bf16x8*>(Xb + swz(16 + ln, cb));
            bf16x8 a2 = *reinterpret_cast<const bf16x8*>(Xb + swz(32 + ln, cb));
            bf16x8 a3 = *reinterpret_cast<const bf16x8*>(Xb + swz(48 + ln, cb));
            #pragma unroll
            for (int jt = 0; jt < 3; ++jt) {
                bf16x8 bb = *reinterpret_cast<const bf16x8*>(
                    Wb + swz((wv * 3 + jt) * 16 + ln, cb));
                acc[0][jt] = MFMA16(a0, bb, acc[0][jt], 0, 0, 0);
                acc[1][jt] = MFMA16(a1, bb, acc[1][jt], 0, 0, 0);
                acc[2][jt] = MFMA16(a2, bb, acc[2][jt], 0, 0, 0);
                acc[3][jt] = MFMA16(a3, bb, acc[3][jt], 0, 0, 0);
            }
        }
        __syncthreads();                    // (B) MFMA reads done
    }

    // ---- epilogue: per owned n-tile (wave-uniform branch) ----
    const float scale = 0.17677669529663687f;
    #pragma unroll
    for (int jt = 0; jt < 3; ++jt) {
        const int n_t = wv * 3 + jt;
        const int m  = n_t >> 2;
        const int hp = (n_t >> 1) & 1;
        const int hf = n_t & 1;
        if (m == 0) {          // Q (pre-scaled), [tok][ch] b16 scatter
            #pragma unroll
            for (int mt = 0; mt < 4; ++mt)
                #pragma unroll
                for (int r = 0; r < 4; ++r)
                    sQ[hp * 64 + mt * 16 + lg * 4 + r][hf * 16 + ln] =
                        f2bf(acc[mt][jt][r] * scale);
        } else if (m == 1) {   // K, [tok][ch] b16 scatter
            #pragma unroll
            for (int mt = 0; mt < 4; ++mt)
                #pragma unroll
                for (int r = 0; r < 4; ++r)
                    sK[hp * 64 + mt * 16 + lg * 4 + r][hf * 16 + ln] =
                        f2bf(acc[mt][jt][r]);
        } else {               // V -> VT[ch][tok], swizzled ushort4
            const int row = hp * 32 + hf * 16 + ln;
            #pragma unroll
            for (int mt = 0; mt < 4; ++mt) {
                ushort4 pv;
                pv.x = f2bf(acc[mt][jt][0]); pv.y = f2bf(acc[mt][jt][1]);
                pv.z = f2bf(acc[mt][jt][2]); pv.w = f2bf(acc[mt][jt][3]);
                *reinterpret_cast<ushort4*>(Vb + swz(row, mt * 32 + lg * 8)) = pv;
            }
        }
    }
    __syncthreads();

    // ---- attention: wave wv owns q-rows 16wv..16wv+15, both heads ----
    const int q = wv * 16 + ln;
    const int prow = wv * 16 + ln;
    #pragma unroll
    for (int hp = 0; hp < 2; ++hp) {
        bf16x8 qf = *reinterpret_cast<const bf16x8*>(&sQ[hp * 64 + q][lg * 8]);
        f32x4 st[4];
        #pragma unroll
        for (int mt = 0; mt < 4; ++mt) {
            bf16x8 kf = *reinterpret_cast<const bf16x8*>(
                &sK[hp * 64 + mt * 16 + ln][lg * 8]);
            st[mt] = MFMA16(kf, qf, (f32x4)(0.f), 0, 0, 0);
        }

        float sv[16];
        float mx = -3.0e38f;
        #pragma unroll
        for (int mt = 0; mt < 4; ++mt) {
            float4 bt = *reinterpret_cast<const float4*>(
                &bias_tab[q * 64 + mt * 16 + lg * 4]);
            float b4[4] = {bt.x, bt.y, bt.z, bt.w};
            #pragma unroll
            for (int r = 0; r < 4; ++r) {
                float s = st[mt][r] + b4[r];
                sv[mt * 4 + r] = s;
                mx = fmaxf(mx, s);
            }
        }
        mx = fmaxf(mx, __shfl_xor(mx, 16));
        mx = fmaxf(mx, __shfl_xor(mx, 32));
        float sum = 0.f;
        #pragma unroll
        for (int i = 0; i < 16; ++i) { sv[i] = __expf(sv[i] - mx); sum += sv[i]; }
        sum += __shfl_xor(sum, 16);
        sum += __shfl_xor(sum, 32);
        const float inv = 1.0f / sum;

        #pragma unroll
        for (int mt = 0; mt < 4; ++mt) {
            ushort4 pv;
            pv.x = f2bf(sv[mt * 4 + 0] * inv);
            pv.y = f2bf(sv[mt * 4 + 1] * inv);
            pv.z = f2bf(sv[mt * 4 + 2] * inv);
            pv.w = f2bf(sv[mt * 4 + 3] * inv);
            *reinterpret_cast<ushort4*>(Pb + swz(prow, mt * 32 + lg * 8)) = pv;
        }

        f32x4 o[2] = {(f32x4)(0.f), (f32x4)(0.f)};
        #pragma unroll
        for (int ks = 0; ks < 2; ++ks) {
            bf16x8 pf = *reinterpret_cast<const bf16x8*>(
                Pb + swz(prow, ks * 64 + lg * 16));
            #pragma unroll
            for (int nt = 0; nt < 2; ++nt) {
                bf16x8 vf = *reinterpret_cast<const bf16x8*>(
                    Vb + swz(hp * 32 + nt * 16 + ln, ks * 64 + lg * 16));
                o[nt] = MFMA16(pf, vf, o[nt], 0, 0, 0);
            }
        }

        #pragma unroll
        for (int nt = 0; nt < 2; ++nt) {
            #pragma unroll
            for (int r = 0; r < 4; ++r) {
                int qi  = wv * 16 + lg * 4 + r;
                int tok = tok_base + ((qi >> 3) << 6) + (qi & 7);
                out[(size_t)tok * 256 + (h0 + hp) * 32 + nt * 16 + ln] = o[nt][r];
            }
        }
    }
}

// =====================================================================
// proj4: in-place out = A @ w_out + b_out (verified, ~17us).
// =====================================================================
__global__ __launch_bounds__(256, 3)
void proj4(float* __restrict__ io,
           const unsigned short* __restrict__ woutT,
           const float* __restrict__ b_out)
{
    __shared__ __align__(16) unsigned short sA[64][264];

    const int tid  = threadIdx.x;
    const int lane = tid & 63;
    const int wv   = tid >> 6;
    const int ln   = lane & 15;
    const int lg   = lane >> 4;
    const size_t m0 = (size_t)blockIdx.x * 64;

    const unsigned short* b0 = woutT + (size_t)((wv +  0) * 16 + ln) * 256 + lg * 8;
    const unsigned short* b1 = woutT + (size_t)((wv +  4) * 16 + ln) * 256 + lg * 8;
    const unsigned short* b2 = woutT + (size_t)((wv +  8) * 16 + ln) * 256 + lg * 8;
    const unsigned short* b3 = woutT + (size_t)((wv + 12) * 16 + ln) * 256 + lg * 8;
    bf16x8 bc0 = *reinterpret_cast<const bf16x8*>(b0);
    bf16x8 bc1 = *reinterpret_cast<const bf16x8*>(b1);
    bf16x8 bc2 = *reinterpret_cast<const bf16x8*>(b2);
    bf16x8 bc3 = *reinterpret_cast<const bf16x8*>(b3);

    #pragma unroll
    for (int it = 0; it < 8; ++it) {
        int idx = tid + (it << 8);
        int row = idx >> 5, c8 = idx & 31;
        const float* p = io + (m0 + row) * 256 + c8 * 8;
        float4 a = *reinterpret_cast<const float4*>(p);
        float4 b = *reinterpret_cast<const float4*>(p + 4);
        *reinterpret_cast<bf16x8*>(&sA[row][c8 * 8]) = cvt8(a, b);
    }
    __syncthreads();

    f32x4 acc[4][4];
    #pragma unroll
    for (int m = 0; m < 4; ++m)
        #pragma unroll
        for (int j = 0; j < 4; ++j) acc[m][j] = (f32x4)(0.f);

    #pragma unroll
    for (int st = 0; st < 8; ++st) {
        const int ko = st * 32 + lg * 8;
        bf16x8 a0 = *reinterpret_cast<const bf16x8*>(&sA[     ln][ko]);
        bf16x8 a1 = *reinterpret_cast<const bf16x8*>(&sA[16 + ln][ko]);
        bf16x8 a2 = *reinterpret_cast<const bf16x8*>(&sA[32 + ln][ko]);
        bf16x8 a3 = *reinterpret_cast<const bf16x8*>(&sA[48 + ln][ko]);
        bf16x8 bn0 = bc0, bn1 = bc1, bn2 = bc2, bn3 = bc3;
        if (st < 7) {
            bn0 = *reinterpret_cast<const bf16x8*>(b0 + (st + 1) * 32);
            bn1 = *reinterpret_cast<const bf16x8*>(b1 + (st + 1) * 32);
            bn2 = *reinterpret_cast<const bf16x8*>(b2 + (st + 1) * 32);
            bn3 = *reinterpret_cast<const bf16x8*>(b3 + (st + 1) * 32);
        }
        acc[0][0] = MFMA16(a0, bc0, acc[0][0], 0, 0, 0);
        acc[1][0] = MFMA16(a1, bc0, acc[1][0], 0, 0, 0);
        acc[2][0] = MFMA16(a2, bc0, acc[2][0], 0, 0, 0);
        acc[3][0] = MFMA16(a3, bc0, acc[3][0], 0, 0, 0);
        acc[0][1] = MFMA16(a0, bc1, acc[0][1], 0, 0, 0);
        acc[1][1] = MFMA16(a1, bc1, acc[1][1], 0, 0, 0);
        acc[2][1] = MFMA16(a2, bc1, acc[2][1], 0, 0, 0);
        acc[3][1] = MFMA16(a3, bc1, acc[3][1], 0, 0, 0);
        acc[0][2] = MFMA16(a0, bc2, acc[0][2], 0, 0, 0);
        acc[1][2] = MFMA16(a1, bc2, acc[1][2], 0, 0, 0);
        acc[2][2] = MFMA16(a2, bc2, acc[2][2], 0, 0, 0);
        acc[3][2] = MFMA16(a3, bc2, acc[3][2], 0, 0, 0);
        acc[0][3] = MFMA16(a0, bc3, acc[0][3], 0, 0, 0);
        acc[1][3] = MFMA16(a1, bc3, acc[1][3], 0, 0, 0);
        acc[2][3] = MFMA16(a2, bc3, acc[2][3], 0, 0, 0);
        acc[3][3] = MFMA16(a3, bc3, acc[3][3], 0, 0, 0);
        bc0 = bn0; bc1 = bn1; bc2 = bn2; bc3 = bn3;
    }

    #pragma unroll
    for (int j = 0; j < 4; ++j) {
        int nt = wv + 4 * j;
        float bias = b_out[nt * 16 + ln];
        #pragma unroll
        for (int m = 0; m < 4; ++m)
            #pragma unroll
            for (int r = 0; r < 4; ++r)
                io[(m0 + m * 16 + lg * 4 + r) * 256 + nt * 16 + ln] =
                    acc[m][j][r] + bias;
    }
}

// =====================================================================
// Fallback (round-3 verified kernels) if ws_size < WS_NEED.
// =====================================================================
__device__ __forceinline__ bf16x8 ldsFrag(const unsigned short* p) {
    return *reinterpret_cast<const bf16x8*>(p);
}

__global__ __launch_bounds__(256, 2)
void winattn_fb(const float* __restrict__ x,
                const float* __restrict__ w_qkv,
                const float* __restrict__ pe,
                float* __restrict__ attn_out)
{
    __shared__ __align__(16) unsigned short sX[64][264];
    __shared__ __align__(16) unsigned short sW[96][72];
    __shared__ __align__(16) unsigned short sQ[64][40];
    __shared__ __align__(16) unsigned short sK[64][40];
    __shared__ __align__(16) unsigned short sVT[32][72];
    __shared__ float sPE[225];
    unsigned short* sP = &sX[0][0];

    const int tid  = threadIdx.x;
    const int lane = tid & 63;
    const int wv   = tid >> 6;
    const int ln   = lane & 15;
    const int lg   = lane >> 4;

    const int h   = blockIdx.x & 7;
    const int wid = blockIdx.x >> 3;
    const int blw = wid >> 6;
    const int whr = (wid >> 3) & 7;
    const int wwc = wid & 7;
    const int tok_base = blw * 4096 + whr * 512 + wwc * 8;

    if (tid < 225) sPE[tid] = pe[tid];

    #pragma unroll
    for (int it = 0; it < 16; ++it) {
        int g = tid + (it << 8);
        int row = g >> 6, f4 = g & 63;
        int tok = tok_base + ((row >> 3) << 6) + (row & 7);
        float4 v = *reinterpret_cast<const float4*>(x + (size_t)tok * 256 + f4 * 4);
        ushort4 u;
        u.x = f2bf(v.x); u.y = f2bf(v.y); u.z = f2bf(v.z); u.w = f2bf(v.w);
        *reinterpret_cast<ushort4*>(&sX[row][f4 << 2]) = u;
    }

    auto stage_w = [&](int kc) {
        #pragma unroll
        for (int it = 0; it < 8; ++it) {
            int g = tid + (it << 8);
            int k = g >> 5, c = g & 31;
            if (c < 24) {
                int m = c >> 3, f4 = c & 7;
                float4 v = *reinterpret_cast<const float4*>(
                    w_qkv + (size_t)(kc * 64 + k) * 768 + m * 256 + h * 32 + f4 * 4);
                float vals[4] = {v.x, v.y, v.z, v.w};
                int n0 = m * 32 + f4 * 4;
                #pragma unroll
                for (int e0 = 0; e0 < 4; ++e0) {
                    int e = (e0 + lane) & 3;
                    sW[n0 + e][k] = f2bf(vals[e]);
                }
            }
        }
    };

    stage_w(0);
    __syncthreads();

    f32x4 acc[6];
    #pragma unroll
    for (int nt = 0; nt < 6; ++nt) acc[nt] = (f32x4)(0.f);

    for (int kc = 0; kc < 4; ++kc) {
        #pragma unroll
        for (int ks = 0; ks < 2; ++ks) {
            bf16x8 a = ldsFrag(&sX[wv * 16 + ln][kc * 64 + ks * 32 + lg * 8]);
            #pragma unroll
            for (int nt = 0; nt < 6; ++nt) {
                bf16x8 b = ldsFrag(&sW[nt * 16 + ln][ks * 32 + lg * 8]);
                acc[nt] = MFMA16(a, b, acc[nt], 0, 0, 0);
            }
        }
        if (kc < 3) { __syncthreads(); stage_w(kc + 1); __syncthreads(); }
    }

    #pragma unroll
    for (int nt = 0; nt < 4; ++nt)
        #pragma unroll
        for (int r = 0; r < 4; ++r) {
            int row = wv * 16 + lg * 4 + r;
            unsigned short bv = f2bf(acc[nt][r]);
            if (nt < 2) sQ[row][nt * 16 + ln] = bv;
            else        sK[row][(nt - 2) * 16 + ln] = bv;
        }
    #pragma unroll
    for (int nt = 4; nt < 6; ++nt) {
        ushort4 pv;
        pv.x = f2bf(acc[nt][0]); pv.y = f2bf(acc[nt][1]);
        pv.z = f2bf(acc[nt][2]); pv.w = f2bf(acc[nt][3]);
        *reinterpret_cast<ushort4*>(&sVT[(nt - 4) * 16 + ln][wv * 16 + lg * 4]) = pv;
    }
    __syncthreads();

    const f32x4 zero = (f32x4)(0.f);
    bf16x8 qf = ldsFrag(&sQ[wv * 16 + ln][lg * 8]);
    f32x4 st[4];
    #pragma unroll
    for (int mt = 0; mt < 4; ++mt) {
        bf16x8 kf = ldsFrag(&sK[mt * 16 + ln][lg * 8]);
        st[mt] = MFMA16(kf, qf, zero, 0, 0, 0);
    }

    const int q = wv * 16 + ln;
    const int qr = q >> 3, qc = q & 7;
    const float scale = 0.17677669529663687f;
    float sv[16];
    float mx = -3.0e38f;
    #pragma unroll
    for (int mt = 0; mt < 4; ++mt)
        #pragma unroll
        for (int r = 0; r < 4; ++r) {
            int j = mt * 16 + lg * 4 + r;
            int dy = (j >> 3) - qr + 7;
            int dx = (j & 7) - qc + 7;
            float s = st[mt][r] * scale + sPE[dy * 15 + dx];
            sv[mt * 4 + r] = s;
            mx = fmaxf(mx, s);
        }
    mx = fmaxf(mx, __shfl_xor(mx, 16));
    mx = fmaxf(mx, __shfl_xor(mx, 32));
    float sum = 0.f;
    #pragma unroll
    for (int i = 0; i < 16; ++i) { sv[i] = __expf(sv[i] - mx); sum += sv[i]; }
    sum += __shfl_xor(sum, 16);
    sum += __shfl_xor(sum, 32);
    const float inv = 1.0f / sum;

    unsigned short* sPw = sP + wv * (16 * 72) + ln * 72;
    #pragma unroll
    for (int mt = 0; mt < 4; ++mt) {
        ushort4 pv;
        pv.x = f2bf(sv[mt * 4 + 0] * inv);
        pv.y = f2bf(sv[mt * 4 + 1] * inv);
        pv.z = f2bf(sv[mt * 4 + 2] * inv);
        pv.w = f2bf(sv[mt * 4 + 3] * inv);
        *reinterpret_cast<ushort4*>(sPw + mt * 16 + lg * 4) = pv;
    }

    f32x4 o[2] = {zero, zero};
    #pragma unroll
    for (int ks = 0; ks < 2; ++ks) {
        bf16x8 pf = ldsFrag(sPw + ks * 32 + lg * 8);
        #pragma unroll
        for (int nt = 0; nt < 2; ++nt) {
            bf16x8 vf = ldsFrag(&sVT[nt * 16 + ln][ks * 32 + lg * 8]);
            o[nt] = MFMA16(pf, vf, o[nt], 0, 0, 0);
        }
    }
    #pragma unroll
    for (int nt = 0; nt < 2; ++nt)
        #pragma unroll
        for (int r = 0; r < 4; ++r) {
            int qi = wv * 16 + lg * 4 + r;
            int tok = tok_base + ((qi >> 3) << 6) + (qi & 7);
            attn_out[(size_t)tok * 256 + h * 32 + nt * 16 + ln] = o[nt][r];
        }
}

__global__ __launch_bounds__(256, 3)
void proj_fb(float* __restrict__ io,
             const float* __restrict__ w_out,
             const float* __restrict__ b_out)
{
    __shared__ __align__(16) unsigned short sA[64][72];
    __shared__ __align__(16) unsigned short sW2[256][72];
    __shared__ float sB[256];

    const int tid  = threadIdx.x;
    const int lane = tid & 63;
    const int wv   = tid >> 6;
    const int ln   = lane & 15;
    const int lg   = lane >> 4;
    const size_t m0 = (size_t)blockIdx.x * 64;

    sB[tid] = b_out[tid];

    f32x4 acc[16];
    #pragma unroll
    for (int nt = 0; nt < 16; ++nt) acc[nt] = (f32x4)(0.f);

    for (int kc = 0; kc < 4; ++kc) {
        if (kc) __syncthreads();
        #pragma unroll
        for (int it = 0; it < 4; ++it) {
            int g = tid + (it << 8);
            int row = g >> 4, f4 = g & 15;
            float4 v = *reinterpret_cast<const float4*>(
                io + (m0 + row) * 256 + kc * 64 + f4 * 4);
            ushort4 u;
            u.x = f2bf(v.x); u.y = f2bf(v.y); u.z = f2bf(v.z); u.w = f2bf(v.w);
            *reinterpret_cast<ushort4*>(&sA[row][f4 << 2]) = u;
        }
        #pragma unroll
        for (int i = 0; i < 16; ++i) {
            int f4 = ln + 16 * (i & 3);
            int kl = 16 * wv + lg + 4 * (i >> 2);
            float4 v = *reinterpret_cast<const float4*>(
                w_out + (size_t)(kc * 64 + kl) * 256 + f4 * 4);
            float vals[4] = {v.x, v.y, v.z, v.w};
            #pragma unroll
            for (int e0 = 0; e0 < 4; ++e0) {
                int e = (e0 + lane) & 3;
                sW2[f4 * 4 + e][kl] = f2bf(vals[e]);
            }
        }
        __syncthreads();

        #pragma unroll
        for (int ks = 0; ks < 2; ++ks) {
            bf16x8 a = ldsFrag(&sA[wv * 16 + ln][ks * 32 + lg * 8]);
            #pragma unroll
            for (int nt = 0; nt < 16; ++nt) {
                bf16x8 b = ldsFrag(&sW2[nt * 16 + ln][ks * 32 + lg * 8]);
                acc[nt] = MFMA16(a, b, acc[nt], 0, 0, 0);
            }
        }
    }

    #pragma unroll
    for (int nt = 0; nt < 16; ++nt) {
        float bias = sB[nt * 16 + ln];
        #pragma unroll
        for (int r = 0; r < 4; ++r) {
            int row = wv * 16 + lg * 4 + r;
            io[(m0 + row) * 256 + nt * 16 + ln] = acc[nt][r] + bias;
        }
    }
}

extern "C" void kernel_launch(void* const* d_in, const int* in_sizes, int n_in,
                              void* d_out, int out_size, void* d_ws, size_t ws_size,
                              hipStream_t stream) {
    const float* x     = (const float*)d_in[0];
    const float* w_qkv = (const float*)d_in[1];
    const float* w_out = (const float*)d_in[2];
    const float* b_out = (const float*)d_in[3];
    const float* pe    = (const float*)d_in[4];
    (void)in_sizes; (void)n_in; (void)out_size;

    float* out = (float*)d_out;

    if (ws_size >= (size_t)WS_NEED) {
        unsigned short* wsT = (unsigned short*)d_ws;
        float* bias_tab = (float*)((char*)d_ws + 524288);
        prep_kernel<<<dim3(257),  dim3(256), 0, stream>>>(w_qkv, w_out, pe, wsT, bias_tab);
        winattn6   <<<dim3(4096), dim3(256), 0, stream>>>(x, wsT, bias_tab, out);
        proj4      <<<dim3(1024), dim3(256), 0, stream>>>(out, wsT + WOUTT_SHORT_OFF, b_out);
    } else {
        winattn_fb <<<dim3(8192), dim3(256), 0, stream>>>(x, w_qkv, pe, out);
        proj_fb    <<<dim3(1024), dim3(256), 0, stream>>>(out, w_out, b_out);
    }
}